// Round 7
// baseline (1165.494 us; speedup 1.0000x reference)
//
#include <hip/hip_runtime.h>

// ---------------------------------------------------------------------------
// TreeConv GNN. R6: edge-parallel LDS-atomic aggregation.
//   R5 showed gather was latency-bound (FETCH halved, time barely moved).
//   Replace per-node serial gather with: one block per 128-node bucket,
//   fp32 accumulator acc[dim][node] in LDS (odd stride -> ~2-way banks),
//   256 threads stream the bucket's edge range, 8(4) lanes/edge, one uint4
//   bf16 load + 8 ds_add_f32 per lane. No csr/off/fill stage at all.
// Partition: 782 bins of 128 nodes (pack src | (dst&255)<<17, bucket=d>>7).
// Register-tiled MLPs (R4) + bf16 operand compression (R5) unchanged.
// ---------------------------------------------------------------------------

#define NBMAX 800     // max 128-node buckets (n <= 102400)
#define CHUNK 8192    // edges per partition block

__device__ inline unsigned int bfbits(float f) {  // RNE f32 -> bf16 bits
  unsigned int x = __float_as_uint(f);
  return (x + 0x7fffu + ((x >> 16) & 1u)) >> 16;
}
__device__ inline unsigned int packbf(float a, float b) {
  return bfbits(a) | (bfbits(b) << 16);
}
__device__ inline float bflo(unsigned int u) {
  return __uint_as_float(u << 16);
}
__device__ inline float bfhi(unsigned int u) {
  return __uint_as_float(u & 0xffff0000u);
}

__global__ __launch_bounds__(256) void bucket_hist_kernel(
    const int* __restrict__ dst, int* __restrict__ bcnt, int ne, int nb) {
  __shared__ int h[NBMAX];
  for (int i = threadIdx.x; i < nb; i += 256) h[i] = 0;
  __syncthreads();
  for (int e = blockIdx.x * 256 + threadIdx.x; e < ne; e += gridDim.x * 256)
    atomicAdd(&h[dst[e] >> 7], 1);
  __syncthreads();
  for (int i = threadIdx.x; i < nb; i += 256) {
    const int c = h[i];
    if (c) atomicAdd(&bcnt[i], c);
  }
}

// One block, 1024 threads: exclusive scan of bcnt[0..nb) -> boff, init bcur.
__global__ __launch_bounds__(1024) void bucket_scan_kernel(
    const int* __restrict__ bcnt, int* __restrict__ boff,
    int* __restrict__ bcur, int nb, int ne) {
  __shared__ int wsum[16];
  const int lane = threadIdx.x & 63;
  const int wid = threadIdx.x >> 6;
  const int v = (threadIdx.x < nb) ? bcnt[threadIdx.x] : 0;
  int x = v;
#pragma unroll
  for (int s = 1; s < 64; s <<= 1) {
    int t = __shfl_up(x, s, 64);
    if (lane >= s) x += t;
  }
  if (lane == 63) wsum[wid] = x;
  __syncthreads();
  if (wid == 0 && lane < 16) {
    int y = wsum[lane];
#pragma unroll
    for (int s = 1; s < 16; s <<= 1) {
      int t = __shfl_up(y, s, 64);
      if (lane >= s) y += t;
    }
    wsum[lane] = y;
  }
  __syncthreads();
  const int wbase = (wid == 0) ? 0 : wsum[wid - 1];
  const int excl = wbase + x - v;
  if (threadIdx.x < nb) {
    boff[threadIdx.x] = excl;
    bcur[threadIdx.x] = excl;
  }
  if (threadIdx.x == 0) boff[nb] = ne;
}

// Chunked partition: LDS hist+scan (16 bins/lane), bin-ordered LDS staging,
// per-bin global claims, bin-major contiguous copy-out.
__global__ __launch_bounds__(256) void partition_kernel(
    const int* __restrict__ src, const int* __restrict__ dst,
    int* __restrict__ bcur, int* __restrict__ sorted, int ne, int nb) {
  __shared__ int hist[NBMAX];
  __shared__ int lbase[NBMAX];
  __shared__ int gbase[NBMAX];
  __shared__ int cur[NBMAX];
  __shared__ int vals[CHUNK];
  __shared__ unsigned short bins[CHUNK];

  const int tid = threadIdx.x;
  const int e0 = blockIdx.x * CHUNK;
  const int m = min(CHUNK, ne - e0);

  for (int i = tid; i < nb; i += 256) hist[i] = 0;
  __syncthreads();
  for (int i = tid; i < m; i += 256) atomicAdd(&hist[dst[e0 + i] >> 7], 1);
  __syncthreads();

  if (tid < 64) {  // 16 bins per lane -> up to 1024 bins
    int vv[16];
    int tot = 0;
#pragma unroll
    for (int k = 0; k < 16; k++) {
      const int b = tid * 16 + k;
      vv[k] = (b < nb) ? hist[b] : 0;
      tot += vv[k];
    }
    int x = tot;
#pragma unroll
    for (int s = 1; s < 64; s <<= 1) {
      int t = __shfl_up(x, s, 64);
      if ((tid & 63) >= s) x += t;
    }
    int run = x - tot;
#pragma unroll
    for (int k = 0; k < 16; k++) {
      const int b = tid * 16 + k;
      if (b < nb) {
        lbase[b] = run;
        run += vv[k];
      }
    }
  }
  __syncthreads();

  for (int b = tid; b < nb; b += 256) {
    const int c = hist[b];
    cur[b] = lbase[b];
    gbase[b] = c ? atomicAdd(&bcur[b], c) : 0;
  }
  __syncthreads();

  for (int i = tid; i < m; i += 256) {
    const int s = src[e0 + i];
    const int d = dst[e0 + i];
    const int b = d >> 7;
    const int p = atomicAdd(&cur[b], 1);
    vals[p] = s | ((d & 255) << 17);
    bins[p] = (unsigned short)b;
  }
  __syncthreads();

  for (int i = tid; i < m; i += 256) {
    const int b = bins[i];
    sorted[gbase[b] + (i - lbase[b])] = vals[i];
  }
}

// f32 -> packed bf16 (RNE), 4 floats per thread
__global__ __launch_bounds__(256) void f32_to_bf16_kernel(
    const float4* __restrict__ in, uint2* __restrict__ out, int n4) {
  const int i = blockIdx.x * 256 + threadIdx.x;
  if (i < n4) {
    const float4 v = in[i];
    out[i] = make_uint2(packbf(v.x, v.y), packbf(v.z, v.w));
  }
}

// ---------------------------------------------------------------------------
// Edge-parallel aggregation: agg[v] = h[v] + sum_{(u->v)} h[u], h packed bf16.
// DIM=64: block = one 128-node bucket, 8 lanes/edge.
// DIM=32: block = two consecutive buckets (256 nodes), 4 lanes/edge.
// acc[dim][node] in LDS with ODD stride S so per-edge lane fan-out spreads
// banks (~2-way, free per m136). Init with self row; ds_add_f32 per edge.
// ---------------------------------------------------------------------------
template <int DIM>
__global__ __launch_bounds__(256) void gather_edges_kernel(
    const uint4* __restrict__ hbf, const int* __restrict__ sorted,
    const int* __restrict__ boff, float* __restrict__ agg, int n) {
  constexpr int NPBG = (DIM == 64) ? 128 : 256;  // nodes per block
  constexpr int S = (DIM == 64) ? 129 : 257;     // acc stride (odd)
  constexpr int QR = DIM / 8;                    // uint4s per row
  constexpr int SH = (DIM == 64) ? 3 : 2;        // log2(QR)
  __shared__ float acc[DIM * S];
  const int tid = threadIdx.x;
  const int base = blockIdx.x * NPBG;

  int e0, e1;
  if (DIM == 64) {
    e0 = boff[blockIdx.x];
    e1 = boff[blockIdx.x + 1];
  } else {
    e0 = boff[blockIdx.x * 2];
    e1 = boff[blockIdx.x * 2 + 2];
  }

  // init acc[d][node] = own row (self-loop term); 0 for pad nodes
  for (int idx = tid; idx < NPBG * QR; idx += 256) {
    const int node = idx >> SH;
    const int q = idx & (QR - 1);
    const int g = base + node;
    uint4 u = make_uint4(0u, 0u, 0u, 0u);
    if (g < n) u = hbf[(size_t)g * QR + q];
    const unsigned int w[4] = {u.x, u.y, u.z, u.w};
#pragma unroll
    for (int t = 0; t < 4; t++) {
      acc[(q * 8 + 2 * t) * S + node] = bflo(w[t]);
      acc[(q * 8 + 2 * t + 1) * S + node] = bfhi(w[t]);
    }
  }
  __syncthreads();

  // edge-parallel accumulate: QR lanes per edge, each owns 8 dims
  const int p = tid & (QR - 1);
#pragma unroll 2
  for (int i = e0 + (tid >> SH); i < e1; i += (256 >> SH)) {
    const int pv = sorted[i];
    const int s = pv & 0x1FFFF;
    const int local = (pv >> 17) & (NPBG - 1);
    const uint4 u = hbf[(size_t)s * QR + p];
    const unsigned int w[4] = {u.x, u.y, u.z, u.w};
    float* col = &acc[(p * 8) * S + local];
#pragma unroll
    for (int t = 0; t < 4; t++) {
      atomicAdd(col + (2 * t) * S, bflo(w[t]));
      atomicAdd(col + (2 * t + 1) * S, bfhi(w[t]));
    }
  }
  __syncthreads();

  // write agg fp32 coalesced
  constexpr int F4 = DIM / 4;
  for (int idx = tid; idx < NPBG * F4; idx += 256) {
    const int node = idx / F4;
    const int q = idx % F4;
    const int g = base + node;
    if (g < n)
      ((float4*)agg)[(size_t)g * F4 + q] =
          make_float4(acc[(q * 4 + 0) * S + node], acc[(q * 4 + 1) * S + node],
                      acc[(q * 4 + 2) * S + node], acc[(q * 4 + 3) * S + node]);
  }
}

// ---------------------------------------------------------------------------
// Register-tiled fused GEMM pair: out = relu(A@w1 + b1)@w2 + b2
// A: [n x K1] f32, out: [n x 64] (f32, or packed bf16 when OUTBF).
// ---------------------------------------------------------------------------
template <int K1, bool OUTBF>
__global__ __launch_bounds__(256) void mlp_pair_kernel(
    const float* __restrict__ A, const float* __restrict__ w1,
    const float* __restrict__ b1, const float* __restrict__ w2,
    const float* __restrict__ b2, void* __restrict__ out, int n) {
  __shared__ float U[64 * 128];   // As_T (K1 x 128) then Zs_T (64 x 128)
  __shared__ float W1s[K1 * 64];
  __shared__ float W2s[64 * 64];
  const int tid = threadIdx.x;
  const int n0 = blockIdx.x * 128;

  for (int i = tid; i < K1 * 16; i += 256)
    ((float4*)W1s)[i] = ((const float4*)w1)[i];
  for (int i = tid; i < 1024; i += 256)
    ((float4*)W2s)[i] = ((const float4*)w2)[i];

  constexpr int Q = K1 / 4;
  for (int idx = tid; idx < 128 * Q; idx += 256) {
    const int node = idx / Q;
    const int q = idx % Q;
    const int g = n0 + node;
    float4 v = make_float4(0.f, 0.f, 0.f, 0.f);
    if (g < n) v = ((const float4*)A)[(size_t)g * Q + q];
    U[(q * 4 + 0) * 128 + node] = v.x;
    U[(q * 4 + 1) * 128 + node] = v.y;
    U[(q * 4 + 2) * 128 + node] = v.z;
    U[(q * 4 + 3) * 128 + node] = v.w;
  }
  __syncthreads();

  const int tm = tid & 31, tn = tid >> 5;

  float acc[4][8];
  {
    const float4 ba = *(const float4*)(b1 + tn * 8);
    const float4 bb = *(const float4*)(b1 + tn * 8 + 4);
#pragma unroll
    for (int i = 0; i < 4; i++) {
      acc[i][0] = ba.x; acc[i][1] = ba.y; acc[i][2] = ba.z; acc[i][3] = ba.w;
      acc[i][4] = bb.x; acc[i][5] = bb.y; acc[i][6] = bb.z; acc[i][7] = bb.w;
    }
  }
#pragma unroll 8
  for (int k = 0; k < K1; k++) {
    const float4 av = *(const float4*)&U[k * 128 + tm * 4];
    const float4 w0 = *(const float4*)&W1s[k * 64 + tn * 8];
    const float4 w1v = *(const float4*)&W1s[k * 64 + tn * 8 + 4];
    const float a4[4] = {av.x, av.y, av.z, av.w};
    const float wv[8] = {w0.x, w0.y, w0.z, w0.w, w1v.x, w1v.y, w1v.z, w1v.w};
#pragma unroll
    for (int i = 0; i < 4; i++)
#pragma unroll
      for (int j = 0; j < 8; j++) acc[i][j] = fmaf(a4[i], wv[j], acc[i][j]);
  }
#pragma unroll
  for (int i = 0; i < 4; i++)
#pragma unroll
    for (int j = 0; j < 8; j++) acc[i][j] = fmaxf(acc[i][j], 0.f);

  __syncthreads();
#pragma unroll
  for (int j = 0; j < 8; j++)
#pragma unroll
    for (int i = 0; i < 4; i++)
      U[(tn * 8 + j) * 128 + tm * 4 + i] = acc[i][j];
  __syncthreads();

  float acc2[4][8];
  {
    const float4 ba = *(const float4*)(b2 + tn * 8);
    const float4 bb = *(const float4*)(b2 + tn * 8 + 4);
#pragma unroll
    for (int i = 0; i < 4; i++) {
      acc2[i][0] = ba.x; acc2[i][1] = ba.y; acc2[i][2] = ba.z; acc2[i][3] = ba.w;
      acc2[i][4] = bb.x; acc2[i][5] = bb.y; acc2[i][6] = bb.z; acc2[i][7] = bb.w;
    }
  }
#pragma unroll 8
  for (int k = 0; k < 64; k++) {
    const float4 av = *(const float4*)&U[k * 128 + tm * 4];
    const float4 w0 = *(const float4*)&W2s[k * 64 + tn * 8];
    const float4 w1v = *(const float4*)&W2s[k * 64 + tn * 8 + 4];
    const float a4[4] = {av.x, av.y, av.z, av.w};
    const float wv[8] = {w0.x, w0.y, w0.z, w0.w, w1v.x, w1v.y, w1v.z, w1v.w};
#pragma unroll
    for (int i = 0; i < 4; i++)
#pragma unroll
      for (int j = 0; j < 8; j++) acc2[i][j] = fmaf(a4[i], wv[j], acc2[i][j]);
  }

#pragma unroll
  for (int i = 0; i < 4; i++) {
    const int g = n0 + tm * 4 + i;
    if (g < n) {
      if (OUTBF) {
        uint4 u;
        u.x = packbf(acc2[i][0], acc2[i][1]);
        u.y = packbf(acc2[i][2], acc2[i][3]);
        u.z = packbf(acc2[i][4], acc2[i][5]);
        u.w = packbf(acc2[i][6], acc2[i][7]);
        ((uint4*)out)[(size_t)g * 8 + tn] = u;
      } else {
        ((float4*)out)[(size_t)g * 16 + tn * 2] =
            make_float4(acc2[i][0], acc2[i][1], acc2[i][2], acc2[i][3]);
        ((float4*)out)[(size_t)g * 16 + tn * 2 + 1] =
            make_float4(acc2[i][4], acc2[i][5], acc2[i][6], acc2[i][7]);
      }
    }
  }
}

// Classifier: out = relu(A@cw1 + cb1)@cw2 + cb2,  A:[n x 64] f32, out:[n x 16]
__global__ __launch_bounds__(256) void cls_tiled_kernel(
    const float* __restrict__ A, const float* __restrict__ w1,
    const float* __restrict__ b1, const float* __restrict__ w2,
    const float* __restrict__ b2, float* __restrict__ out, int n) {
  __shared__ float U[64 * 128];
  __shared__ float W1s[64 * 64];
  __shared__ float W2s[64 * 16];
  const int tid = threadIdx.x;
  const int n0 = blockIdx.x * 128;

  for (int i = tid; i < 1024; i += 256)
    ((float4*)W1s)[i] = ((const float4*)w1)[i];
  for (int i = tid; i < 256; i += 256)
    ((float4*)W2s)[i] = ((const float4*)w2)[i];

  for (int idx = tid; idx < 128 * 16; idx += 256) {
    const int node = idx >> 4;
    const int q = idx & 15;
    const int g = n0 + node;
    float4 v = make_float4(0.f, 0.f, 0.f, 0.f);
    if (g < n) v = ((const float4*)A)[(size_t)g * 16 + q];
    U[(q * 4 + 0) * 128 + node] = v.x;
    U[(q * 4 + 1) * 128 + node] = v.y;
    U[(q * 4 + 2) * 128 + node] = v.z;
    U[(q * 4 + 3) * 128 + node] = v.w;
  }
  __syncthreads();

  const int tm = tid & 31, tn = tid >> 5;

  float acc[4][8];
  {
    const float4 ba = *(const float4*)(b1 + tn * 8);
    const float4 bb = *(const float4*)(b1 + tn * 8 + 4);
#pragma unroll
    for (int i = 0; i < 4; i++) {
      acc[i][0] = ba.x; acc[i][1] = ba.y; acc[i][2] = ba.z; acc[i][3] = ba.w;
      acc[i][4] = bb.x; acc[i][5] = bb.y; acc[i][6] = bb.z; acc[i][7] = bb.w;
    }
  }
#pragma unroll 8
  for (int k = 0; k < 64; k++) {
    const float4 av = *(const float4*)&U[k * 128 + tm * 4];
    const float4 w0 = *(const float4*)&W1s[k * 64 + tn * 8];
    const float4 w1v = *(const float4*)&W1s[k * 64 + tn * 8 + 4];
    const float a4[4] = {av.x, av.y, av.z, av.w};
    const float wv[8] = {w0.x, w0.y, w0.z, w0.w, w1v.x, w1v.y, w1v.z, w1v.w};
#pragma unroll
    for (int i = 0; i < 4; i++)
#pragma unroll
      for (int j = 0; j < 8; j++) acc[i][j] = fmaf(a4[i], wv[j], acc[i][j]);
  }
#pragma unroll
  for (int i = 0; i < 4; i++)
#pragma unroll
    for (int j = 0; j < 8; j++) acc[i][j] = fmaxf(acc[i][j], 0.f);

  __syncthreads();
#pragma unroll
  for (int j = 0; j < 8; j++)
#pragma unroll
    for (int i = 0; i < 4; i++)
      U[(tn * 8 + j) * 128 + tm * 4 + i] = acc[i][j];
  __syncthreads();

  float acc2[4][2];
  {
    const float b0 = b2[tn * 2], b1v = b2[tn * 2 + 1];
#pragma unroll
    for (int i = 0; i < 4; i++) { acc2[i][0] = b0; acc2[i][1] = b1v; }
  }
#pragma unroll 8
  for (int k = 0; k < 64; k++) {
    const float4 av = *(const float4*)&U[k * 128 + tm * 4];
    const float wa = W2s[k * 16 + tn * 2];
    const float wb = W2s[k * 16 + tn * 2 + 1];
    const float a4[4] = {av.x, av.y, av.z, av.w};
#pragma unroll
    for (int i = 0; i < 4; i++) {
      acc2[i][0] = fmaf(a4[i], wa, acc2[i][0]);
      acc2[i][1] = fmaf(a4[i], wb, acc2[i][1]);
    }
  }
#pragma unroll
  for (int i = 0; i < 4; i++) {
    const int g = n0 + tm * 4 + i;
    if (g < n)
      ((float2*)out)[(size_t)g * 8 + tn] = make_float2(acc2[i][0], acc2[i][1]);
  }
}

extern "C" void kernel_launch(void* const* d_in, const int* in_sizes, int n_in,
                              void* d_out, int out_size, void* d_ws,
                              size_t ws_size, hipStream_t stream) {
  const float* x = (const float*)d_in[0];
  const int* ei = (const int*)d_in[1];
  const float* w1_0 = (const float*)d_in[2];
  const float* b1_0 = (const float*)d_in[3];
  const float* w2_0 = (const float*)d_in[4];
  const float* b2_0 = (const float*)d_in[5];
  const float* w1_1 = (const float*)d_in[6];
  const float* b1_1 = (const float*)d_in[7];
  const float* w2_1 = (const float*)d_in[8];
  const float* b2_1 = (const float*)d_in[9];
  const float* cw1 = (const float*)d_in[10];
  const float* cb1 = (const float*)d_in[11];
  const float* cw2 = (const float*)d_in[12];
  const float* cb2 = (const float*)d_in[13];

  const int n = in_sizes[0] / 32;  // nodes (< 2^17 for packing)
  const int ne = in_sizes[1] / 2;  // edges
  const int* src = ei;
  const int* dst = ei + ne;
  const int nb = (n + 127) / 128;          // 128-node buckets
  const int nb2 = (n + 255) / 256;         // bucket pairs (layer-0 gather)

  // Workspace layout
  float* aggr = (float*)d_ws;                       // n*64 f32 (agg union)
  float* h1 = aggr + (size_t)n * 64;                // n*64 f32
  uint2* xbf = (uint2*)(h1 + (size_t)n * 64);       // n*32 bf16
  uint2* h0bf = xbf + (size_t)n * 8;                // n*64 bf16
  int* sorted = (int*)(h0bf + (size_t)n * 16);      // ne
  int* bcnt = sorted + ne;                          // nb
  int* boff = bcnt + nb;                            // nb+1
  int* bcur = boff + nb + 1;                        // nb

  // --- bucket sort of edges by dst ---
  hipMemsetAsync(bcnt, 0, (size_t)nb * sizeof(int), stream);
  bucket_hist_kernel<<<220, 256, 0, stream>>>(dst, bcnt, ne, nb);
  bucket_scan_kernel<<<1, 1024, 0, stream>>>(bcnt, boff, bcur, nb, ne);
  partition_kernel<<<(ne + CHUNK - 1) / CHUNK, 256, 0, stream>>>(
      src, dst, bcur, sorted, ne, nb);

  // x -> bf16
  {
    const int n4 = n * 8;
    f32_to_bf16_kernel<<<(n4 + 255) / 256, 256, 0, stream>>>(
        (const float4*)x, xbf, n4);
  }

  const int ntile = (n + 127) / 128;

  // --- Layer 0 ---
  gather_edges_kernel<32><<<nb2, 256, 0, stream>>>((const uint4*)xbf, sorted,
                                                   boff, aggr, n);
  mlp_pair_kernel<32, true><<<ntile, 256, 0, stream>>>(aggr, w1_0, b1_0, w2_0,
                                                       b2_0, h0bf, n);

  // --- Layer 1 ---
  gather_edges_kernel<64><<<nb, 256, 0, stream>>>((const uint4*)h0bf, sorted,
                                                  boff, aggr, n);
  mlp_pair_kernel<64, false><<<ntile, 256, 0, stream>>>(aggr, w1_1, b1_1,
                                                        w2_1, b2_1, h1, n);

  // --- Classifier ---
  cls_tiled_kernel<<<ntile, 256, 0, stream>>>(h1, cw1, cb1, cw2, cb2,
                                              (float*)d_out, n);
}

// Round 8
// 215.164 us; speedup vs baseline: 5.4168x; 5.4168x over previous
//
#include <hip/hip_runtime.h>

// ---------------------------------------------------------------------------
// TreeConv GNN. R7: revert R6's LDS-atomic gather (LDS-atomic-throughput
// bound, 11x regression). Back to R5 pipeline; gather restructured for
// latency: 8(4) lanes/node each owning one uint4 (8 bf16), 4-deep manual
// unroll -> ~8x more independent loads in flight per wave.
// CSR build (R3) + register-tiled MLPs (R4) + bf16 operands (R5) unchanged.
// ---------------------------------------------------------------------------

#define NPB 256       // nodes per bucket; bucket id = dst >> 8
#define NBMAX 512     // max buckets (n <= 131072)
#define CHUNK 8192    // edges per partition block

__device__ inline unsigned int bfbits(float f) {  // RNE f32 -> bf16 bits
  unsigned int x = __float_as_uint(f);
  return (x + 0x7fffu + ((x >> 16) & 1u)) >> 16;
}
__device__ inline unsigned int packbf(float a, float b) {
  return bfbits(a) | (bfbits(b) << 16);
}
__device__ inline float bflo(unsigned int u) {
  return __uint_as_float(u << 16);
}
__device__ inline float bfhi(unsigned int u) {
  return __uint_as_float(u & 0xffff0000u);
}

__global__ __launch_bounds__(256) void bucket_hist_kernel(
    const int* __restrict__ dst, int* __restrict__ bcnt, int ne, int nb) {
  __shared__ int h[NBMAX];
  for (int i = threadIdx.x; i < nb; i += 256) h[i] = 0;
  __syncthreads();
  for (int e = blockIdx.x * 256 + threadIdx.x; e < ne; e += gridDim.x * 256)
    atomicAdd(&h[dst[e] >> 8], 1);
  __syncthreads();
  for (int i = threadIdx.x; i < nb; i += 256) {
    const int c = h[i];
    if (c) atomicAdd(&bcnt[i], c);
  }
}

__global__ __launch_bounds__(512) void bucket_scan_kernel(
    const int* __restrict__ bcnt, int* __restrict__ boff,
    int* __restrict__ bcur, int nb, int ne) {
  __shared__ int wsum[8];
  const int lane = threadIdx.x & 63;
  const int wid = threadIdx.x >> 6;
  const int v = (threadIdx.x < nb) ? bcnt[threadIdx.x] : 0;
  int x = v;
#pragma unroll
  for (int s = 1; s < 64; s <<= 1) {
    int t = __shfl_up(x, s, 64);
    if (lane >= s) x += t;
  }
  if (lane == 63) wsum[wid] = x;
  __syncthreads();
  if (wid == 0 && lane < 8) {
    int y = wsum[lane];
#pragma unroll
    for (int s = 1; s < 8; s <<= 1) {
      int t = __shfl_up(y, s, 64);
      if (lane >= s) y += t;
    }
    wsum[lane] = y;
  }
  __syncthreads();
  const int wbase = (wid == 0) ? 0 : wsum[wid - 1];
  const int excl = wbase + x - v;
  if (threadIdx.x < nb) {
    boff[threadIdx.x] = excl;
    bcur[threadIdx.x] = excl;
  }
  if (threadIdx.x == 0) boff[nb] = ne;
}

__global__ __launch_bounds__(256) void partition_kernel(
    const int* __restrict__ src, const int* __restrict__ dst,
    int* __restrict__ bcur, int* __restrict__ sorted, int ne, int nb) {
  __shared__ int hist[NBMAX];
  __shared__ int lbase[NBMAX];
  __shared__ int gbase[NBMAX];
  __shared__ int cur[NBMAX];
  __shared__ int vals[CHUNK];
  __shared__ unsigned short bins[CHUNK];

  const int tid = threadIdx.x;
  const int e0 = blockIdx.x * CHUNK;
  const int m = min(CHUNK, ne - e0);

  for (int i = tid; i < nb; i += 256) hist[i] = 0;
  __syncthreads();
  for (int i = tid; i < m; i += 256) atomicAdd(&hist[dst[e0 + i] >> 8], 1);
  __syncthreads();

  if (tid < 64) {
    int v8[8];
    int tot = 0;
#pragma unroll
    for (int k = 0; k < 8; k++) {
      const int b = tid * 8 + k;
      v8[k] = (b < nb) ? hist[b] : 0;
      tot += v8[k];
    }
    int x = tot;
#pragma unroll
    for (int s = 1; s < 64; s <<= 1) {
      int t = __shfl_up(x, s, 64);
      if ((tid & 63) >= s) x += t;
    }
    int run = x - tot;
#pragma unroll
    for (int k = 0; k < 8; k++) {
      const int b = tid * 8 + k;
      if (b < nb) {
        lbase[b] = run;
        run += v8[k];
      }
    }
  }
  __syncthreads();

  for (int b = tid; b < nb; b += 256) {
    const int c = hist[b];
    cur[b] = lbase[b];
    gbase[b] = c ? atomicAdd(&bcur[b], c) : 0;
  }
  __syncthreads();

  for (int i = tid; i < m; i += 256) {
    const int s = src[e0 + i];
    const int d = dst[e0 + i];
    const int b = d >> 8;
    const int p = atomicAdd(&cur[b], 1);
    vals[p] = s | ((d & 255) << 17);
    bins[p] = (unsigned short)b;
  }
  __syncthreads();

  for (int i = tid; i < m; i += 256) {
    const int b = bins[i];
    sorted[gbase[b] + (i - lbase[b])] = vals[i];
  }
}

__global__ __launch_bounds__(256) void fill_bucket_kernel(
    const int* __restrict__ sorted, const int* __restrict__ boff,
    int* __restrict__ off, int* __restrict__ csr, int n, int ne) {
  __shared__ int hist[NPB];
  __shared__ int cur[NPB];
  __shared__ int wsum[4];
  const int tid = threadIdx.x;
  const int b = blockIdx.x;
  const int e0 = boff[b];
  const int m = boff[b + 1] - e0;

  hist[tid] = 0;
  __syncthreads();
  for (int i = tid; i < m; i += 256) atomicAdd(&hist[sorted[e0 + i] >> 17], 1);
  __syncthreads();

  const int lane = tid & 63;
  const int wid = tid >> 6;
  const int v = hist[tid];
  int x = v;
#pragma unroll
  for (int s = 1; s < 64; s <<= 1) {
    int t = __shfl_up(x, s, 64);
    if (lane >= s) x += t;
  }
  if (lane == 63) wsum[wid] = x;
  __syncthreads();
  if (tid == 0) {
    int s = 0;
#pragma unroll
    for (int k = 0; k < 4; k++) {
      const int t = wsum[k];
      wsum[k] = s;
      s += t;
    }
  }
  __syncthreads();
  const int excl = wsum[wid] + x - v;
  cur[tid] = excl;
  const int node = b * NPB + tid;
  if (node < n) off[node] = e0 + excl;
  if (b == 0 && tid == 0) off[n] = ne;
  __syncthreads();

  for (int i = tid; i < m; i += 256) {
    const int pv = sorted[e0 + i];
    const int r = atomicAdd(&cur[pv >> 17], 1);
    csr[e0 + r] = pv & 0x1FFFF;
  }
}

// f32 -> packed bf16 (RNE), 4 floats per thread
__global__ __launch_bounds__(256) void f32_to_bf16_kernel(
    const float4* __restrict__ in, uint2* __restrict__ out, int n4) {
  const int i = blockIdx.x * 256 + threadIdx.x;
  if (i < n4) {
    const float4 v = in[i];
    out[i] = make_uint2(packbf(v.x, v.y), packbf(v.z, v.w));
  }
}

// ---------------------------------------------------------------------------
// Latency-optimized gather: agg[v] = h[v] + sum_{u in adj(v)} h[u].
// h packed bf16, row = L uint4s (L=8 -> D=64, L=4 -> D=32). L lanes per
// node, each lane owns one uint4 (8 bf16 -> 8 fp32 accs). 4-deep unroll:
// 4 independent row loads in flight per lane.
// ---------------------------------------------------------------------------
template <int L>
__global__ __launch_bounds__(256) void gather2_kernel(
    const uint4* __restrict__ hbf, const int* __restrict__ off,
    const int* __restrict__ csr, float* __restrict__ agg, int n_nodes) {
  const int t = blockIdx.x * 256 + threadIdx.x;
  const int gid = t / L;
  const int lane = t & (L - 1);
  if (gid >= n_nodes) return;

  uint4 v = hbf[(size_t)gid * L + lane];
  float a0 = bflo(v.x), a1 = bfhi(v.x), a2 = bflo(v.y), a3 = bfhi(v.y);
  float a4 = bflo(v.z), a5 = bfhi(v.z), a6 = bflo(v.w), a7 = bfhi(v.w);

  const int e0 = off[gid], e1 = off[gid + 1];
  int e = e0;
  for (; e + 3 < e1; e += 4) {
    const int s0 = csr[e + 0];
    const int s1 = csr[e + 1];
    const int s2 = csr[e + 2];
    const int s3 = csr[e + 3];
    const uint4 u0 = hbf[(size_t)s0 * L + lane];
    const uint4 u1 = hbf[(size_t)s1 * L + lane];
    const uint4 u2 = hbf[(size_t)s2 * L + lane];
    const uint4 u3 = hbf[(size_t)s3 * L + lane];
    a0 += bflo(u0.x); a1 += bfhi(u0.x); a2 += bflo(u0.y); a3 += bfhi(u0.y);
    a4 += bflo(u0.z); a5 += bfhi(u0.z); a6 += bflo(u0.w); a7 += bfhi(u0.w);
    a0 += bflo(u1.x); a1 += bfhi(u1.x); a2 += bflo(u1.y); a3 += bfhi(u1.y);
    a4 += bflo(u1.z); a5 += bfhi(u1.z); a6 += bflo(u1.w); a7 += bfhi(u1.w);
    a0 += bflo(u2.x); a1 += bfhi(u2.x); a2 += bflo(u2.y); a3 += bfhi(u2.y);
    a4 += bflo(u2.z); a5 += bfhi(u2.z); a6 += bflo(u2.w); a7 += bfhi(u2.w);
    a0 += bflo(u3.x); a1 += bfhi(u3.x); a2 += bflo(u3.y); a3 += bfhi(u3.y);
    a4 += bflo(u3.z); a5 += bfhi(u3.z); a6 += bflo(u3.w); a7 += bfhi(u3.w);
  }
  for (; e < e1; ++e) {
    const int s = csr[e];
    const uint4 u = hbf[(size_t)s * L + lane];
    a0 += bflo(u.x); a1 += bfhi(u.x); a2 += bflo(u.y); a3 += bfhi(u.y);
    a4 += bflo(u.z); a5 += bfhi(u.z); a6 += bflo(u.w); a7 += bfhi(u.w);
  }

  float4* op = (float4*)(agg + (size_t)gid * (8 * L)) + lane * 2;
  op[0] = make_float4(a0, a1, a2, a3);
  op[1] = make_float4(a4, a5, a6, a7);
}

// ---------------------------------------------------------------------------
// Register-tiled fused GEMM pair: out = relu(A@w1 + b1)@w2 + b2
// A: [n x K1] f32, out: [n x 64] (f32, or packed bf16 when OUTBF).
// ---------------------------------------------------------------------------
template <int K1, bool OUTBF>
__global__ __launch_bounds__(256) void mlp_pair_kernel(
    const float* __restrict__ A, const float* __restrict__ w1,
    const float* __restrict__ b1, const float* __restrict__ w2,
    const float* __restrict__ b2, void* __restrict__ out, int n) {
  __shared__ float U[64 * 128];   // As_T (K1 x 128) then Zs_T (64 x 128)
  __shared__ float W1s[K1 * 64];
  __shared__ float W2s[64 * 64];
  const int tid = threadIdx.x;
  const int n0 = blockIdx.x * 128;

  for (int i = tid; i < K1 * 16; i += 256)
    ((float4*)W1s)[i] = ((const float4*)w1)[i];
  for (int i = tid; i < 1024; i += 256)
    ((float4*)W2s)[i] = ((const float4*)w2)[i];

  constexpr int Q = K1 / 4;
  for (int idx = tid; idx < 128 * Q; idx += 256) {
    const int node = idx / Q;
    const int q = idx % Q;
    const int g = n0 + node;
    float4 v = make_float4(0.f, 0.f, 0.f, 0.f);
    if (g < n) v = ((const float4*)A)[(size_t)g * Q + q];
    U[(q * 4 + 0) * 128 + node] = v.x;
    U[(q * 4 + 1) * 128 + node] = v.y;
    U[(q * 4 + 2) * 128 + node] = v.z;
    U[(q * 4 + 3) * 128 + node] = v.w;
  }
  __syncthreads();

  const int tm = tid & 31, tn = tid >> 5;

  float acc[4][8];
  {
    const float4 ba = *(const float4*)(b1 + tn * 8);
    const float4 bb = *(const float4*)(b1 + tn * 8 + 4);
#pragma unroll
    for (int i = 0; i < 4; i++) {
      acc[i][0] = ba.x; acc[i][1] = ba.y; acc[i][2] = ba.z; acc[i][3] = ba.w;
      acc[i][4] = bb.x; acc[i][5] = bb.y; acc[i][6] = bb.z; acc[i][7] = bb.w;
    }
  }
#pragma unroll 8
  for (int k = 0; k < K1; k++) {
    const float4 av = *(const float4*)&U[k * 128 + tm * 4];
    const float4 w0 = *(const float4*)&W1s[k * 64 + tn * 8];
    const float4 w1v = *(const float4*)&W1s[k * 64 + tn * 8 + 4];
    const float a4[4] = {av.x, av.y, av.z, av.w};
    const float wv[8] = {w0.x, w0.y, w0.z, w0.w, w1v.x, w1v.y, w1v.z, w1v.w};
#pragma unroll
    for (int i = 0; i < 4; i++)
#pragma unroll
      for (int j = 0; j < 8; j++) acc[i][j] = fmaf(a4[i], wv[j], acc[i][j]);
  }
#pragma unroll
  for (int i = 0; i < 4; i++)
#pragma unroll
    for (int j = 0; j < 8; j++) acc[i][j] = fmaxf(acc[i][j], 0.f);

  __syncthreads();
#pragma unroll
  for (int j = 0; j < 8; j++)
#pragma unroll
    for (int i = 0; i < 4; i++)
      U[(tn * 8 + j) * 128 + tm * 4 + i] = acc[i][j];
  __syncthreads();

  float acc2[4][8];
  {
    const float4 ba = *(const float4*)(b2 + tn * 8);
    const float4 bb = *(const float4*)(b2 + tn * 8 + 4);
#pragma unroll
    for (int i = 0; i < 4; i++) {
      acc2[i][0] = ba.x; acc2[i][1] = ba.y; acc2[i][2] = ba.z; acc2[i][3] = ba.w;
      acc2[i][4] = bb.x; acc2[i][5] = bb.y; acc2[i][6] = bb.z; acc2[i][7] = bb.w;
    }
  }
#pragma unroll 8
  for (int k = 0; k < 64; k++) {
    const float4 av = *(const float4*)&U[k * 128 + tm * 4];
    const float4 w0 = *(const float4*)&W2s[k * 64 + tn * 8];
    const float4 w1v = *(const float4*)&W2s[k * 64 + tn * 8 + 4];
    const float a4[4] = {av.x, av.y, av.z, av.w};
    const float wv[8] = {w0.x, w0.y, w0.z, w0.w, w1v.x, w1v.y, w1v.z, w1v.w};
#pragma unroll
    for (int i = 0; i < 4; i++)
#pragma unroll
      for (int j = 0; j < 8; j++) acc2[i][j] = fmaf(a4[i], wv[j], acc2[i][j]);
  }

#pragma unroll
  for (int i = 0; i < 4; i++) {
    const int g = n0 + tm * 4 + i;
    if (g < n) {
      if (OUTBF) {
        uint4 u;
        u.x = packbf(acc2[i][0], acc2[i][1]);
        u.y = packbf(acc2[i][2], acc2[i][3]);
        u.z = packbf(acc2[i][4], acc2[i][5]);
        u.w = packbf(acc2[i][6], acc2[i][7]);
        ((uint4*)out)[(size_t)g * 8 + tn] = u;
      } else {
        ((float4*)out)[(size_t)g * 16 + tn * 2] =
            make_float4(acc2[i][0], acc2[i][1], acc2[i][2], acc2[i][3]);
        ((float4*)out)[(size_t)g * 16 + tn * 2 + 1] =
            make_float4(acc2[i][4], acc2[i][5], acc2[i][6], acc2[i][7]);
      }
    }
  }
}

// Classifier: out = relu(A@cw1 + cb1)@cw2 + cb2,  A:[n x 64] f32, out:[n x 16]
__global__ __launch_bounds__(256) void cls_tiled_kernel(
    const float* __restrict__ A, const float* __restrict__ w1,
    const float* __restrict__ b1, const float* __restrict__ w2,
    const float* __restrict__ b2, float* __restrict__ out, int n) {
  __shared__ float U[64 * 128];
  __shared__ float W1s[64 * 64];
  __shared__ float W2s[64 * 16];
  const int tid = threadIdx.x;
  const int n0 = blockIdx.x * 128;

  for (int i = tid; i < 1024; i += 256)
    ((float4*)W1s)[i] = ((const float4*)w1)[i];
  for (int i = tid; i < 256; i += 256)
    ((float4*)W2s)[i] = ((const float4*)w2)[i];

  for (int idx = tid; idx < 128 * 16; idx += 256) {
    const int node = idx >> 4;
    const int q = idx & 15;
    const int g = n0 + node;
    float4 v = make_float4(0.f, 0.f, 0.f, 0.f);
    if (g < n) v = ((const float4*)A)[(size_t)g * 16 + q];
    U[(q * 4 + 0) * 128 + node] = v.x;
    U[(q * 4 + 1) * 128 + node] = v.y;
    U[(q * 4 + 2) * 128 + node] = v.z;
    U[(q * 4 + 3) * 128 + node] = v.w;
  }
  __syncthreads();

  const int tm = tid & 31, tn = tid >> 5;

  float acc[4][8];
  {
    const float4 ba = *(const float4*)(b1 + tn * 8);
    const float4 bb = *(const float4*)(b1 + tn * 8 + 4);
#pragma unroll
    for (int i = 0; i < 4; i++) {
      acc[i][0] = ba.x; acc[i][1] = ba.y; acc[i][2] = ba.z; acc[i][3] = ba.w;
      acc[i][4] = bb.x; acc[i][5] = bb.y; acc[i][6] = bb.z; acc[i][7] = bb.w;
    }
  }
#pragma unroll 8
  for (int k = 0; k < 64; k++) {
    const float4 av = *(const float4*)&U[k * 128 + tm * 4];
    const float4 w0 = *(const float4*)&W1s[k * 64 + tn * 8];
    const float4 w1v = *(const float4*)&W1s[k * 64 + tn * 8 + 4];
    const float a4[4] = {av.x, av.y, av.z, av.w};
    const float wv[8] = {w0.x, w0.y, w0.z, w0.w, w1v.x, w1v.y, w1v.z, w1v.w};
#pragma unroll
    for (int i = 0; i < 4; i++)
#pragma unroll
      for (int j = 0; j < 8; j++) acc[i][j] = fmaf(a4[i], wv[j], acc[i][j]);
  }
#pragma unroll
  for (int i = 0; i < 4; i++)
#pragma unroll
    for (int j = 0; j < 8; j++) acc[i][j] = fmaxf(acc[i][j], 0.f);

  __syncthreads();
#pragma unroll
  for (int j = 0; j < 8; j++)
#pragma unroll
    for (int i = 0; i < 4; i++)
      U[(tn * 8 + j) * 128 + tm * 4 + i] = acc[i][j];
  __syncthreads();

  float acc2[4][2];
  {
    const float b0 = b2[tn * 2], b1v = b2[tn * 2 + 1];
#pragma unroll
    for (int i = 0; i < 4; i++) { acc2[i][0] = b0; acc2[i][1] = b1v; }
  }
#pragma unroll 8
  for (int k = 0; k < 64; k++) {
    const float4 av = *(const float4*)&U[k * 128 + tm * 4];
    const float wa = W2s[k * 16 + tn * 2];
    const float wb = W2s[k * 16 + tn * 2 + 1];
    const float a4[4] = {av.x, av.y, av.z, av.w};
#pragma unroll
    for (int i = 0; i < 4; i++) {
      acc2[i][0] = fmaf(a4[i], wa, acc2[i][0]);
      acc2[i][1] = fmaf(a4[i], wb, acc2[i][1]);
    }
  }
#pragma unroll
  for (int i = 0; i < 4; i++) {
    const int g = n0 + tm * 4 + i;
    if (g < n)
      ((float2*)out)[(size_t)g * 8 + tn] = make_float2(acc2[i][0], acc2[i][1]);
  }
}

extern "C" void kernel_launch(void* const* d_in, const int* in_sizes, int n_in,
                              void* d_out, int out_size, void* d_ws,
                              size_t ws_size, hipStream_t stream) {
  const float* x = (const float*)d_in[0];
  const int* ei = (const int*)d_in[1];
  const float* w1_0 = (const float*)d_in[2];
  const float* b1_0 = (const float*)d_in[3];
  const float* w2_0 = (const float*)d_in[4];
  const float* b2_0 = (const float*)d_in[5];
  const float* w1_1 = (const float*)d_in[6];
  const float* b1_1 = (const float*)d_in[7];
  const float* w2_1 = (const float*)d_in[8];
  const float* b2_1 = (const float*)d_in[9];
  const float* cw1 = (const float*)d_in[10];
  const float* cb1 = (const float*)d_in[11];
  const float* cw2 = (const float*)d_in[12];
  const float* cb2 = (const float*)d_in[13];

  const int n = in_sizes[0] / 32;  // nodes (< 2^17 for packing)
  const int ne = in_sizes[1] / 2;  // edges
  const int* src = ei;
  const int* dst = ei + ne;
  const int nb = (n + NPB - 1) / NPB;

  // Workspace layout
  float* aggr = (float*)d_ws;                       // n*64 f32 (agg union)
  float* h1 = aggr + (size_t)n * 64;                // n*64 f32
  uint2* xbf = (uint2*)(h1 + (size_t)n * 64);       // n*32 bf16
  uint2* h0bf = xbf + (size_t)n * 8;                // n*64 bf16
  int* sorted = (int*)(h0bf + (size_t)n * 16);      // ne
  int* csr = sorted + ne;                           // ne
  int* off = csr + ne;                              // n+1
  int* bcnt = off + n + 1;                          // nb
  int* boff = bcnt + nb;                            // nb+1
  int* bcur = boff + nb + 1;                        // nb

  // --- CSR build ---
  hipMemsetAsync(bcnt, 0, (size_t)nb * sizeof(int), stream);
  bucket_hist_kernel<<<220, 256, 0, stream>>>(dst, bcnt, ne, nb);
  bucket_scan_kernel<<<1, 512, 0, stream>>>(bcnt, boff, bcur, nb, ne);
  partition_kernel<<<(ne + CHUNK - 1) / CHUNK, 256, 0, stream>>>(
      src, dst, bcur, sorted, ne, nb);
  fill_bucket_kernel<<<nb, 256, 0, stream>>>(sorted, boff, off, csr, n, ne);

  // x -> bf16
  {
    const int n4 = n * 8;
    f32_to_bf16_kernel<<<(n4 + 255) / 256, 256, 0, stream>>>(
        (const float4*)x, xbf, n4);
  }

  const int ntile = (n + 127) / 128;

  // --- Layer 0 ---  (row = 4 uint4s, 4 lanes/node)
  gather2_kernel<4><<<((size_t)n * 4 + 255) / 256, 256, 0, stream>>>(
      (const uint4*)xbf, off, csr, aggr, n);
  mlp_pair_kernel<32, true><<<ntile, 256, 0, stream>>>(aggr, w1_0, b1_0, w2_0,
                                                       b2_0, h0bf, n);

  // --- Layer 1 ---  (row = 8 uint4s, 8 lanes/node)
  gather2_kernel<8><<<((size_t)n * 8 + 255) / 256, 256, 0, stream>>>(
      (const uint4*)h0bf, off, csr, aggr, n);
  mlp_pair_kernel<64, false><<<ntile, 256, 0, stream>>>(aggr, w1_1, b1_1,
                                                        w2_1, b2_1, h1, n);

  // --- Classifier ---
  cls_tiled_kernel<<<ntile, 256, 0, stream>>>(h1, cw1, cb1, cw2, cb2,
                                              (float*)d_out, n);
}

// Round 9
// 152.028 us; speedup vs baseline: 7.6663x; 1.4153x over previous
//
#include <hip/hip_runtime.h>

// ---------------------------------------------------------------------------
// TreeConv GNN. R8: MFMA MLPs (mfma_f32_16x16x32_bf16).
//   R7 profile: mlp_pair = 46us, VALUBusy 25%, occupancy 13% -> LDS-latency
//   bound VALU GEMM. Replace with per-wave MFMA: weights repacked once into
//   fragment-linear bf16 (38 frags), A = packed-bf16 node rows (gathers now
//   emit bf16 agg directly), z roundtrips LDS [128][72] bf16 (16B-aligned,
//   ~conflict-free). CSR build + gather2 structure unchanged from R7.
// ---------------------------------------------------------------------------

#define NPB 256       // nodes per bucket; bucket id = dst >> 8
#define NBMAX 512     // max buckets (n <= 131072)
#define CHUNK 8192    // edges per partition block

typedef __attribute__((ext_vector_type(8))) short short8;
typedef __attribute__((ext_vector_type(4))) float f32x4;

__device__ inline unsigned int bfbits(float f) {  // RNE f32 -> bf16 bits
  unsigned int x = __float_as_uint(f);
  return (x + 0x7fffu + ((x >> 16) & 1u)) >> 16;
}
__device__ inline unsigned int packbf(float a, float b) {
  return bfbits(a) | (bfbits(b) << 16);
}
__device__ inline float bflo(unsigned int u) {
  return __uint_as_float(u << 16);
}
__device__ inline float bfhi(unsigned int u) {
  return __uint_as_float(u & 0xffff0000u);
}

// ---------------- CSR build (unchanged from R7) ----------------

__global__ __launch_bounds__(256) void bucket_hist_kernel(
    const int* __restrict__ dst, int* __restrict__ bcnt, int ne, int nb) {
  __shared__ int h[NBMAX];
  for (int i = threadIdx.x; i < nb; i += 256) h[i] = 0;
  __syncthreads();
  for (int e = blockIdx.x * 256 + threadIdx.x; e < ne; e += gridDim.x * 256)
    atomicAdd(&h[dst[e] >> 8], 1);
  __syncthreads();
  for (int i = threadIdx.x; i < nb; i += 256) {
    const int c = h[i];
    if (c) atomicAdd(&bcnt[i], c);
  }
}

__global__ __launch_bounds__(512) void bucket_scan_kernel(
    const int* __restrict__ bcnt, int* __restrict__ boff,
    int* __restrict__ bcur, int nb, int ne) {
  __shared__ int wsum[8];
  const int lane = threadIdx.x & 63;
  const int wid = threadIdx.x >> 6;
  const int v = (threadIdx.x < nb) ? bcnt[threadIdx.x] : 0;
  int x = v;
#pragma unroll
  for (int s = 1; s < 64; s <<= 1) {
    int t = __shfl_up(x, s, 64);
    if (lane >= s) x += t;
  }
  if (lane == 63) wsum[wid] = x;
  __syncthreads();
  if (wid == 0 && lane < 8) {
    int y = wsum[lane];
#pragma unroll
    for (int s = 1; s < 8; s <<= 1) {
      int t = __shfl_up(y, s, 64);
      if (lane >= s) y += t;
    }
    wsum[lane] = y;
  }
  __syncthreads();
  const int wbase = (wid == 0) ? 0 : wsum[wid - 1];
  const int excl = wbase + x - v;
  if (threadIdx.x < nb) {
    boff[threadIdx.x] = excl;
    bcur[threadIdx.x] = excl;
  }
  if (threadIdx.x == 0) boff[nb] = ne;
}

__global__ __launch_bounds__(256) void partition_kernel(
    const int* __restrict__ src, const int* __restrict__ dst,
    int* __restrict__ bcur, int* __restrict__ sorted, int ne, int nb) {
  __shared__ int hist[NBMAX];
  __shared__ int lbase[NBMAX];
  __shared__ int gbase[NBMAX];
  __shared__ int cur[NBMAX];
  __shared__ int vals[CHUNK];
  __shared__ unsigned short bins[CHUNK];

  const int tid = threadIdx.x;
  const int e0 = blockIdx.x * CHUNK;
  const int m = min(CHUNK, ne - e0);

  for (int i = tid; i < nb; i += 256) hist[i] = 0;
  __syncthreads();
  for (int i = tid; i < m; i += 256) atomicAdd(&hist[dst[e0 + i] >> 8], 1);
  __syncthreads();

  if (tid < 64) {
    int v8[8];
    int tot = 0;
#pragma unroll
    for (int k = 0; k < 8; k++) {
      const int b = tid * 8 + k;
      v8[k] = (b < nb) ? hist[b] : 0;
      tot += v8[k];
    }
    int x = tot;
#pragma unroll
    for (int s = 1; s < 64; s <<= 1) {
      int t = __shfl_up(x, s, 64);
      if ((tid & 63) >= s) x += t;
    }
    int run = x - tot;
#pragma unroll
    for (int k = 0; k < 8; k++) {
      const int b = tid * 8 + k;
      if (b < nb) {
        lbase[b] = run;
        run += v8[k];
      }
    }
  }
  __syncthreads();

  for (int b = tid; b < nb; b += 256) {
    const int c = hist[b];
    cur[b] = lbase[b];
    gbase[b] = c ? atomicAdd(&bcur[b], c) : 0;
  }
  __syncthreads();

  for (int i = tid; i < m; i += 256) {
    const int s = src[e0 + i];
    const int d = dst[e0 + i];
    const int b = d >> 8;
    const int p = atomicAdd(&cur[b], 1);
    vals[p] = s | ((d & 255) << 17);
    bins[p] = (unsigned short)b;
  }
  __syncthreads();

  for (int i = tid; i < m; i += 256) {
    const int b = bins[i];
    sorted[gbase[b] + (i - lbase[b])] = vals[i];
  }
}

__global__ __launch_bounds__(256) void fill_bucket_kernel(
    const int* __restrict__ sorted, const int* __restrict__ boff,
    int* __restrict__ off, int* __restrict__ csr, int n, int ne) {
  __shared__ int hist[NPB];
  __shared__ int cur[NPB];
  __shared__ int wsum[4];
  const int tid = threadIdx.x;
  const int b = blockIdx.x;
  const int e0 = boff[b];
  const int m = boff[b + 1] - e0;

  hist[tid] = 0;
  __syncthreads();
  for (int i = tid; i < m; i += 256) atomicAdd(&hist[sorted[e0 + i] >> 17], 1);
  __syncthreads();

  const int lane = tid & 63;
  const int wid = tid >> 6;
  const int v = hist[tid];
  int x = v;
#pragma unroll
  for (int s = 1; s < 64; s <<= 1) {
    int t = __shfl_up(x, s, 64);
    if (lane >= s) x += t;
  }
  if (lane == 63) wsum[wid] = x;
  __syncthreads();
  if (tid == 0) {
    int s = 0;
#pragma unroll
    for (int k = 0; k < 4; k++) {
      const int t = wsum[k];
      wsum[k] = s;
      s += t;
    }
  }
  __syncthreads();
  const int excl = wsum[wid] + x - v;
  cur[tid] = excl;
  const int node = b * NPB + tid;
  if (node < n) off[node] = e0 + excl;
  if (b == 0 && tid == 0) off[n] = ne;
  __syncthreads();

  for (int i = tid; i < m; i += 256) {
    const int pv = sorted[e0 + i];
    const int r = atomicAdd(&cur[pv >> 17], 1);
    csr[e0 + r] = pv & 0x1FFFF;
  }
}

// f32 -> packed bf16 (RNE), 4 floats per thread
__global__ __launch_bounds__(256) void f32_to_bf16_kernel(
    const float4* __restrict__ in, uint2* __restrict__ out, int n4) {
  const int i = blockIdx.x * 256 + threadIdx.x;
  if (i < n4) {
    const float4 v = in[i];
    out[i] = make_uint2(packbf(v.x, v.y), packbf(v.z, v.w));
  }
}

// ---------------------------------------------------------------------------
// Weight repack: fragment-linear bf16 B-operands for mfma_16x16x32_bf16.
// Frag f, lane l holds W[kb*32 + (l>>4)*8 + i][t*16 + (l&15)], i=0..7.
// Layout in wfrag (uint4): [0,4)=W1_0  [4,12)=W2_0  [12,20)=W1_1
// [20,28)=W2_1  [28,36)=CW1  [36,38)=CW2(N=16, t=0, f0=kb).
// ---------------------------------------------------------------------------
__global__ __launch_bounds__(256) void repack_w_kernel(
    const float* __restrict__ w1_0, const float* __restrict__ w2_0,
    const float* __restrict__ w1_1, const float* __restrict__ w2_1,
    const float* __restrict__ cw1, const float* __restrict__ cw2,
    uint4* __restrict__ wfrag) {
  for (int idx = threadIdx.x; idx < 38 * 64; idx += 256) {
    const int f = idx >> 6, l = idx & 63;
    const float* W;
    int N = 64, f0;
    if (f < 4) { W = w1_0; f0 = f; }
    else if (f < 12) { W = w2_0; f0 = f - 4; }
    else if (f < 20) { W = w1_1; f0 = f - 12; }
    else if (f < 28) { W = w2_1; f0 = f - 20; }
    else if (f < 36) { W = cw1; f0 = f - 28; }
    else { W = cw2; f0 = f - 36; N = 16; }
    int kb, t;
    if (N == 16) { kb = f0; t = 0; } else { kb = f0 >> 2; t = f0 & 3; }
    const int k0 = kb * 32 + (l >> 4) * 8;
    const int col = t * 16 + (l & 15);
    unsigned int p[4];
#pragma unroll
    for (int j = 0; j < 4; j++)
      p[j] = packbf(W[(k0 + 2 * j) * N + col], W[(k0 + 2 * j + 1) * N + col]);
    wfrag[idx] = make_uint4(p[0], p[1], p[2], p[3]);
  }
}

// ---------------------------------------------------------------------------
// Gather (latency-optimized, from R7), now emits packed bf16 rows.
// ---------------------------------------------------------------------------
template <int L>
__global__ __launch_bounds__(256) void gather2_kernel(
    const uint4* __restrict__ hbf, const int* __restrict__ off,
    const int* __restrict__ csr, uint4* __restrict__ agg, int n_nodes) {
  const int t = blockIdx.x * 256 + threadIdx.x;
  const int gid = t / L;
  const int lane = t & (L - 1);
  if (gid >= n_nodes) return;

  uint4 v = hbf[(size_t)gid * L + lane];
  float a0 = bflo(v.x), a1 = bfhi(v.x), a2 = bflo(v.y), a3 = bfhi(v.y);
  float a4 = bflo(v.z), a5 = bfhi(v.z), a6 = bflo(v.w), a7 = bfhi(v.w);

  const int e0 = off[gid], e1 = off[gid + 1];
  int e = e0;
  for (; e + 3 < e1; e += 4) {
    const int s0 = csr[e + 0];
    const int s1 = csr[e + 1];
    const int s2 = csr[e + 2];
    const int s3 = csr[e + 3];
    const uint4 u0 = hbf[(size_t)s0 * L + lane];
    const uint4 u1 = hbf[(size_t)s1 * L + lane];
    const uint4 u2 = hbf[(size_t)s2 * L + lane];
    const uint4 u3 = hbf[(size_t)s3 * L + lane];
    a0 += bflo(u0.x); a1 += bfhi(u0.x); a2 += bflo(u0.y); a3 += bfhi(u0.y);
    a4 += bflo(u0.z); a5 += bfhi(u0.z); a6 += bflo(u0.w); a7 += bfhi(u0.w);
    a0 += bflo(u1.x); a1 += bfhi(u1.x); a2 += bflo(u1.y); a3 += bfhi(u1.y);
    a4 += bflo(u1.z); a5 += bfhi(u1.z); a6 += bflo(u1.w); a7 += bfhi(u1.w);
    a0 += bflo(u2.x); a1 += bfhi(u2.x); a2 += bflo(u2.y); a3 += bfhi(u2.y);
    a4 += bflo(u2.z); a5 += bfhi(u2.z); a6 += bflo(u2.w); a7 += bfhi(u2.w);
    a0 += bflo(u3.x); a1 += bfhi(u3.x); a2 += bflo(u3.y); a3 += bfhi(u3.y);
    a4 += bflo(u3.z); a5 += bfhi(u3.z); a6 += bflo(u3.w); a7 += bfhi(u3.w);
  }
  for (; e < e1; ++e) {
    const int s = csr[e];
    const uint4 u = hbf[(size_t)s * L + lane];
    a0 += bflo(u.x); a1 += bfhi(u.x); a2 += bflo(u.y); a3 += bfhi(u.y);
    a4 += bflo(u.z); a5 += bfhi(u.z); a6 += bflo(u.w); a7 += bfhi(u.w);
  }

  agg[(size_t)gid * L + lane] = make_uint4(packbf(a0, a1), packbf(a2, a3),
                                           packbf(a4, a5), packbf(a6, a7));
}

// ---------------------------------------------------------------------------
// MFMA fused MLP: out = relu(A@W1 + b1) @ W2 + b2.
// A: [n][K1] packed bf16. Block = 128 nodes, 4 waves x 2 M-tiles(16).
// GEMM1 -> z in LDS bf16 [128][72] (stride 72 hw: 16B-aligned reads,
// <=2 lanes/bank on stage writes). GEMM2 (K=64): NT2 N-tiles.
// OUTBF: out bf16 [n][64]; else f32 [n][16] (classifier).
// MFMA maps (gfx950 16x16x32): A row=l&15 k=(l>>4)*8+i; B col=l&15 same k;
// D col=l&15 row=(l>>4)*4+reg [verified].
// ---------------------------------------------------------------------------
template <int K1, int NT2, bool OUTBF>
__global__ __launch_bounds__(256) void mlp_mfma_kernel(
    const short8* __restrict__ Abf, const short8* __restrict__ wf1,
    const float* __restrict__ b1, const short8* __restrict__ wf2,
    const float* __restrict__ b2, void* __restrict__ out, int n) {
  constexpr int KB1 = K1 / 32;
  __shared__ unsigned short zs[128 * 72];
  const int tid = threadIdx.x;
  const int lane = tid & 63;
  const int wid = tid >> 6;
  const int n0 = blockIdx.x * 128;
  const int l15 = lane & 15, lh = lane >> 4;

  // ---- GEMM1 ----
  short8 bf1[KB1 * 4];
#pragma unroll
  for (int f = 0; f < KB1 * 4; f++) bf1[f] = wf1[f * 64 + lane];

  f32x4 acc[2][4];
#pragma unroll
  for (int m = 0; m < 2; m++)
#pragma unroll
    for (int t = 0; t < 4; t++) acc[m][t] = (f32x4){0.f, 0.f, 0.f, 0.f};

#pragma unroll
  for (int m = 0; m < 2; m++) {
    const int row = n0 + wid * 32 + m * 16 + l15;
#pragma unroll
    for (int kb = 0; kb < KB1; kb++) {
      short8 a = {};
      if (row < n) a = Abf[(size_t)row * (K1 / 8) + kb * 4 + lh];
#pragma unroll
      for (int t = 0; t < 4; t++)
        acc[m][t] = __builtin_amdgcn_mfma_f32_16x16x32_bf16(a, bf1[kb * 4 + t],
                                                            acc[m][t], 0, 0, 0);
    }
  }

  // bias + relu + stage z (bf16)
  float b1v[4];
#pragma unroll
  for (int t = 0; t < 4; t++) b1v[t] = b1[t * 16 + l15];
#pragma unroll
  for (int m = 0; m < 2; m++)
#pragma unroll
    for (int t = 0; t < 4; t++)
#pragma unroll
      for (int r = 0; r < 4; r++) {
        const float z = fmaxf(acc[m][t][r] + b1v[t], 0.f);
        zs[(wid * 32 + m * 16 + lh * 4 + r) * 72 + t * 16 + l15] =
            (unsigned short)bfbits(z);
      }
  __syncthreads();

  // ---- GEMM2 (K=64) ----
  constexpr int NF2 = 2 * NT2;
  short8 bf2[NF2];
#pragma unroll
  for (int f = 0; f < NF2; f++) bf2[f] = wf2[f * 64 + lane];

  f32x4 acc2[2][NT2];
#pragma unroll
  for (int m = 0; m < 2; m++)
#pragma unroll
    for (int t = 0; t < NT2; t++) acc2[m][t] = (f32x4){0.f, 0.f, 0.f, 0.f};

#pragma unroll
  for (int m = 0; m < 2; m++) {
#pragma unroll
    for (int kb = 0; kb < 2; kb++) {
      const short8 a2 = *(const short8*)&zs[(wid * 32 + m * 16 + l15) * 72 +
                                            kb * 32 + lh * 8];
#pragma unroll
      for (int t = 0; t < NT2; t++)
        acc2[m][t] = __builtin_amdgcn_mfma_f32_16x16x32_bf16(
            a2, bf2[kb * NT2 + t], acc2[m][t], 0, 0, 0);
    }
  }
  __syncthreads();

  // ---- epilogue ----
  if (OUTBF) {
#pragma unroll
    for (int m = 0; m < 2; m++)
#pragma unroll
      for (int t = 0; t < 4; t++) {
        const float bb = b2[t * 16 + l15];
#pragma unroll
        for (int r = 0; r < 4; r++)
          zs[(wid * 32 + m * 16 + lh * 4 + r) * 72 + t * 16 + l15] =
              (unsigned short)bfbits(acc2[m][t][r] + bb);
      }
    __syncthreads();
    for (int i = tid; i < 128 * 8; i += 256) {
      const int row = i >> 3, q = i & 7;
      if (n0 + row < n)
        ((short8*)out)[(size_t)(n0 + row) * 8 + q] =
            *(const short8*)&zs[row * 72 + q * 8];
    }
  } else {
    float* zf = (float*)zs;  // [128][20] f32
    const float bb = b2[l15];
#pragma unroll
    for (int m = 0; m < 2; m++)
#pragma unroll
      for (int r = 0; r < 4; r++)
        zf[(wid * 32 + m * 16 + lh * 4 + r) * 20 + l15] = acc2[m][0][r] + bb;
    __syncthreads();
    for (int i = tid; i < 512; i += 256) {
      const int row = i >> 2, q = i & 3;
      if (n0 + row < n)
        ((float4*)out)[(size_t)(n0 + row) * 4 + q] =
            *(const float4*)&zf[row * 20 + q * 4];
    }
  }
}

extern "C" void kernel_launch(void* const* d_in, const int* in_sizes, int n_in,
                              void* d_out, int out_size, void* d_ws,
                              size_t ws_size, hipStream_t stream) {
  const float* x = (const float*)d_in[0];
  const int* ei = (const int*)d_in[1];
  const float* w1_0 = (const float*)d_in[2];
  const float* b1_0 = (const float*)d_in[3];
  const float* w2_0 = (const float*)d_in[4];
  const float* b2_0 = (const float*)d_in[5];
  const float* w1_1 = (const float*)d_in[6];
  const float* b1_1 = (const float*)d_in[7];
  const float* w2_1 = (const float*)d_in[8];
  const float* b2_1 = (const float*)d_in[9];
  const float* cw1 = (const float*)d_in[10];
  const float* cb1 = (const float*)d_in[11];
  const float* cw2 = (const float*)d_in[12];
  const float* cb2 = (const float*)d_in[13];

  const int n = in_sizes[0] / 32;  // nodes (< 2^17 for packing)
  const int ne = in_sizes[1] / 2;  // edges
  const int* src = ei;
  const int* dst = ei + ne;
  const int nb = (n + NPB - 1) / NPB;

  // Workspace layout (16B-aligned uint4 region first, then ints)
  uint4* aggbf = (uint4*)d_ws;                 // n*8  (bf16 [n][<=64])
  uint4* h0bf = aggbf + (size_t)n * 8;         // n*8  (bf16 [n][64])
  uint4* h1bf = h0bf + (size_t)n * 8;          // n*8  (bf16 [n][64])
  uint4* xbf = h1bf + (size_t)n * 8;           // n*4  (bf16 [n][32])
  uint4* wfrag = xbf + (size_t)n * 4;          // 38*64
  int* sorted = (int*)(wfrag + 38 * 64);       // ne
  int* csr = sorted + ne;                      // ne
  int* off = csr + ne;                         // n+1
  int* bcnt = off + n + 1;                     // nb
  int* boff = bcnt + nb;                       // nb+1
  int* bcur = boff + nb + 1;                   // nb

  // --- CSR build ---
  hipMemsetAsync(bcnt, 0, (size_t)nb * sizeof(int), stream);
  bucket_hist_kernel<<<220, 256, 0, stream>>>(dst, bcnt, ne, nb);
  bucket_scan_kernel<<<1, 512, 0, stream>>>(bcnt, boff, bcur, nb, ne);
  partition_kernel<<<(ne + CHUNK - 1) / CHUNK, 256, 0, stream>>>(
      src, dst, bcur, sorted, ne, nb);
  fill_bucket_kernel<<<nb, 256, 0, stream>>>(sorted, boff, off, csr, n, ne);

  // x -> bf16 ; weight fragment repack
  {
    const int n4 = n * 8;
    f32_to_bf16_kernel<<<(n4 + 255) / 256, 256, 0, stream>>>(
        (const float4*)x, (uint2*)xbf, n4);
  }
  repack_w_kernel<<<1, 256, 0, stream>>>(w1_0, w2_0, w1_1, w2_1, cw1, cw2,
                                         wfrag);

  const int ntile = (n + 127) / 128;
  const short8* wf = (const short8*)wfrag;

  // --- Layer 0 ---
  gather2_kernel<4><<<((size_t)n * 4 + 255) / 256, 256, 0, stream>>>(
      xbf, off, csr, aggbf, n);
  mlp_mfma_kernel<32, 4, true><<<ntile, 256, 0, stream>>>(
      (const short8*)aggbf, wf + 0 * 64, b1_0, wf + 4 * 64, b2_0, h0bf, n);

  // --- Layer 1 ---
  gather2_kernel<8><<<((size_t)n * 8 + 255) / 256, 256, 0, stream>>>(
      h0bf, off, csr, aggbf, n);
  mlp_mfma_kernel<64, 4, true><<<ntile, 256, 0, stream>>>(
      (const short8*)aggbf, wf + 12 * 64, b1_1, wf + 20 * 64, b2_1, h1bf, n);

  // --- Classifier ---
  mlp_mfma_kernel<64, 1, false><<<ntile, 256, 0, stream>>>(
      (const short8*)h1bf, wf + 28 * 64, cb1, wf + 36 * 64, cb2, d_out, n);
}

// Round 10
// 146.961 us; speedup vs baseline: 7.9306x; 1.0345x over previous
//
#include <hip/hip_runtime.h>

// ---------------------------------------------------------------------------
// TreeConv GNN. R9: kill the 42us hipMemsetAsync.
//   R8 profile: __amd_rocclr_fillBufferAligned (our 1.5KB bcnt memset!) was
//   the TOP dispatch at 42-43us per replay. Replace with a one-block custom
//   zero kernel. Also fold f32->bf16 conversion + weight repack into one
//   launch. MFMA MLPs (R8), gather2 (R7), CSR build (R3) unchanged.
// ---------------------------------------------------------------------------

#define NPB 256       // nodes per bucket; bucket id = dst >> 8
#define NBMAX 512     // max buckets (n <= 131072)
#define CHUNK 8192    // edges per partition block

typedef __attribute__((ext_vector_type(8))) short short8;
typedef __attribute__((ext_vector_type(4))) float f32x4;

__device__ inline unsigned int bfbits(float f) {  // RNE f32 -> bf16 bits
  unsigned int x = __float_as_uint(f);
  return (x + 0x7fffu + ((x >> 16) & 1u)) >> 16;
}
__device__ inline unsigned int packbf(float a, float b) {
  return bfbits(a) | (bfbits(b) << 16);
}
__device__ inline float bflo(unsigned int u) {
  return __uint_as_float(u << 16);
}
__device__ inline float bfhi(unsigned int u) {
  return __uint_as_float(u & 0xffff0000u);
}

__global__ __launch_bounds__(256) void zero_kernel(int* __restrict__ p,
                                                   int m) {
  for (int i = threadIdx.x; i < m; i += 256) p[i] = 0;
}

// ---------------- CSR build ----------------

__global__ __launch_bounds__(256) void bucket_hist_kernel(
    const int* __restrict__ dst, int* __restrict__ bcnt, int ne, int nb) {
  __shared__ int h[NBMAX];
  for (int i = threadIdx.x; i < nb; i += 256) h[i] = 0;
  __syncthreads();
  for (int e = blockIdx.x * 256 + threadIdx.x; e < ne; e += gridDim.x * 256)
    atomicAdd(&h[dst[e] >> 8], 1);
  __syncthreads();
  for (int i = threadIdx.x; i < nb; i += 256) {
    const int c = h[i];
    if (c) atomicAdd(&bcnt[i], c);
  }
}

__global__ __launch_bounds__(512) void bucket_scan_kernel(
    const int* __restrict__ bcnt, int* __restrict__ boff,
    int* __restrict__ bcur, int nb, int ne) {
  __shared__ int wsum[8];
  const int lane = threadIdx.x & 63;
  const int wid = threadIdx.x >> 6;
  const int v = (threadIdx.x < nb) ? bcnt[threadIdx.x] : 0;
  int x = v;
#pragma unroll
  for (int s = 1; s < 64; s <<= 1) {
    int t = __shfl_up(x, s, 64);
    if (lane >= s) x += t;
  }
  if (lane == 63) wsum[wid] = x;
  __syncthreads();
  if (wid == 0 && lane < 8) {
    int y = wsum[lane];
#pragma unroll
    for (int s = 1; s < 8; s <<= 1) {
      int t = __shfl_up(y, s, 64);
      if (lane >= s) y += t;
    }
    wsum[lane] = y;
  }
  __syncthreads();
  const int wbase = (wid == 0) ? 0 : wsum[wid - 1];
  const int excl = wbase + x - v;
  if (threadIdx.x < nb) {
    boff[threadIdx.x] = excl;
    bcur[threadIdx.x] = excl;
  }
  if (threadIdx.x == 0) boff[nb] = ne;
}

__global__ __launch_bounds__(256) void partition_kernel(
    const int* __restrict__ src, const int* __restrict__ dst,
    int* __restrict__ bcur, int* __restrict__ sorted, int ne, int nb) {
  __shared__ int hist[NBMAX];
  __shared__ int lbase[NBMAX];
  __shared__ int gbase[NBMAX];
  __shared__ int cur[NBMAX];
  __shared__ int vals[CHUNK];
  __shared__ unsigned short bins[CHUNK];

  const int tid = threadIdx.x;
  const int e0 = blockIdx.x * CHUNK;
  const int m = min(CHUNK, ne - e0);

  for (int i = tid; i < nb; i += 256) hist[i] = 0;
  __syncthreads();
  for (int i = tid; i < m; i += 256) atomicAdd(&hist[dst[e0 + i] >> 8], 1);
  __syncthreads();

  if (tid < 64) {
    int v8[8];
    int tot = 0;
#pragma unroll
    for (int k = 0; k < 8; k++) {
      const int b = tid * 8 + k;
      v8[k] = (b < nb) ? hist[b] : 0;
      tot += v8[k];
    }
    int x = tot;
#pragma unroll
    for (int s = 1; s < 64; s <<= 1) {
      int t = __shfl_up(x, s, 64);
      if ((tid & 63) >= s) x += t;
    }
    int run = x - tot;
#pragma unroll
    for (int k = 0; k < 8; k++) {
      const int b = tid * 8 + k;
      if (b < nb) {
        lbase[b] = run;
        run += v8[k];
      }
    }
  }
  __syncthreads();

  for (int b = tid; b < nb; b += 256) {
    const int c = hist[b];
    cur[b] = lbase[b];
    gbase[b] = c ? atomicAdd(&bcur[b], c) : 0;
  }
  __syncthreads();

  for (int i = tid; i < m; i += 256) {
    const int s = src[e0 + i];
    const int d = dst[e0 + i];
    const int b = d >> 8;
    const int p = atomicAdd(&cur[b], 1);
    vals[p] = s | ((d & 255) << 17);
    bins[p] = (unsigned short)b;
  }
  __syncthreads();

  for (int i = tid; i < m; i += 256) {
    const int b = bins[i];
    sorted[gbase[b] + (i - lbase[b])] = vals[i];
  }
}

__global__ __launch_bounds__(256) void fill_bucket_kernel(
    const int* __restrict__ sorted, const int* __restrict__ boff,
    int* __restrict__ off, int* __restrict__ csr, int n, int ne) {
  __shared__ int hist[NPB];
  __shared__ int cur[NPB];
  __shared__ int wsum[4];
  const int tid = threadIdx.x;
  const int b = blockIdx.x;
  const int e0 = boff[b];
  const int m = boff[b + 1] - e0;

  hist[tid] = 0;
  __syncthreads();
  for (int i = tid; i < m; i += 256) atomicAdd(&hist[sorted[e0 + i] >> 17], 1);
  __syncthreads();

  const int lane = tid & 63;
  const int wid = tid >> 6;
  const int v = hist[tid];
  int x = v;
#pragma unroll
  for (int s = 1; s < 64; s <<= 1) {
    int t = __shfl_up(x, s, 64);
    if (lane >= s) x += t;
  }
  if (lane == 63) wsum[wid] = x;
  __syncthreads();
  if (tid == 0) {
    int s = 0;
#pragma unroll
    for (int k = 0; k < 4; k++) {
      const int t = wsum[k];
      wsum[k] = s;
      s += t;
    }
  }
  __syncthreads();
  const int excl = wsum[wid] + x - v;
  cur[tid] = excl;
  const int node = b * NPB + tid;
  if (node < n) off[node] = e0 + excl;
  if (b == 0 && tid == 0) off[n] = ne;
  __syncthreads();

  for (int i = tid; i < m; i += 256) {
    const int pv = sorted[e0 + i];
    const int r = atomicAdd(&cur[pv >> 17], 1);
    csr[e0 + r] = pv & 0x1FFFF;
  }
}

// ---------------------------------------------------------------------------
// Fused prep: block 0 repacks weights into MFMA fragment-linear bf16;
// blocks 1.. convert x to packed bf16.
// Frag f, lane l holds W[kb*32 + (l>>4)*8 + i][t*16 + (l&15)], i=0..7.
// wfrag layout: [0,4)=W1_0 [4,12)=W2_0 [12,20)=W1_1 [20,28)=W2_1
// [28,36)=CW1 [36,38)=CW2 (N=16).
// ---------------------------------------------------------------------------
__global__ __launch_bounds__(256) void prep_kernel(
    const float4* __restrict__ x, uint2* __restrict__ xbf, int n4,
    const float* __restrict__ w1_0, const float* __restrict__ w2_0,
    const float* __restrict__ w1_1, const float* __restrict__ w2_1,
    const float* __restrict__ cw1, const float* __restrict__ cw2,
    uint4* __restrict__ wfrag) {
  if (blockIdx.x == 0) {
    for (int idx = threadIdx.x; idx < 38 * 64; idx += 256) {
      const int f = idx >> 6, l = idx & 63;
      const float* W;
      int N = 64, f0;
      if (f < 4) { W = w1_0; f0 = f; }
      else if (f < 12) { W = w2_0; f0 = f - 4; }
      else if (f < 20) { W = w1_1; f0 = f - 12; }
      else if (f < 28) { W = w2_1; f0 = f - 20; }
      else if (f < 36) { W = cw1; f0 = f - 28; }
      else { W = cw2; f0 = f - 36; N = 16; }
      int kb, t;
      if (N == 16) { kb = f0; t = 0; } else { kb = f0 >> 2; t = f0 & 3; }
      const int k0 = kb * 32 + (l >> 4) * 8;
      const int col = t * 16 + (l & 15);
      unsigned int p[4];
#pragma unroll
      for (int j = 0; j < 4; j++)
        p[j] =
            packbf(W[(k0 + 2 * j) * N + col], W[(k0 + 2 * j + 1) * N + col]);
      wfrag[idx] = make_uint4(p[0], p[1], p[2], p[3]);
    }
    return;
  }
  const int i = (blockIdx.x - 1) * 256 + threadIdx.x;
  if (i < n4) {
    const float4 v = x[i];
    xbf[i] = make_uint2(packbf(v.x, v.y), packbf(v.z, v.w));
  }
}

// ---------------------------------------------------------------------------
// Gather (latency-optimized), packed bf16 in/out.
// ---------------------------------------------------------------------------
template <int L>
__global__ __launch_bounds__(256) void gather2_kernel(
    const uint4* __restrict__ hbf, const int* __restrict__ off,
    const int* __restrict__ csr, uint4* __restrict__ agg, int n_nodes) {
  const int t = blockIdx.x * 256 + threadIdx.x;
  const int gid = t / L;
  const int lane = t & (L - 1);
  if (gid >= n_nodes) return;

  uint4 v = hbf[(size_t)gid * L + lane];
  float a0 = bflo(v.x), a1 = bfhi(v.x), a2 = bflo(v.y), a3 = bfhi(v.y);
  float a4 = bflo(v.z), a5 = bfhi(v.z), a6 = bflo(v.w), a7 = bfhi(v.w);

  const int e0 = off[gid], e1 = off[gid + 1];
  int e = e0;
  for (; e + 3 < e1; e += 4) {
    const int s0 = csr[e + 0];
    const int s1 = csr[e + 1];
    const int s2 = csr[e + 2];
    const int s3 = csr[e + 3];
    const uint4 u0 = hbf[(size_t)s0 * L + lane];
    const uint4 u1 = hbf[(size_t)s1 * L + lane];
    const uint4 u2 = hbf[(size_t)s2 * L + lane];
    const uint4 u3 = hbf[(size_t)s3 * L + lane];
    a0 += bflo(u0.x); a1 += bfhi(u0.x); a2 += bflo(u0.y); a3 += bfhi(u0.y);
    a4 += bflo(u0.z); a5 += bfhi(u0.z); a6 += bflo(u0.w); a7 += bfhi(u0.w);
    a0 += bflo(u1.x); a1 += bfhi(u1.x); a2 += bflo(u1.y); a3 += bfhi(u1.y);
    a4 += bflo(u1.z); a5 += bfhi(u1.z); a6 += bflo(u1.w); a7 += bfhi(u1.w);
    a0 += bflo(u2.x); a1 += bfhi(u2.x); a2 += bflo(u2.y); a3 += bfhi(u2.y);
    a4 += bflo(u2.z); a5 += bfhi(u2.z); a6 += bflo(u2.w); a7 += bfhi(u2.w);
    a0 += bflo(u3.x); a1 += bfhi(u3.x); a2 += bflo(u3.y); a3 += bfhi(u3.y);
    a4 += bflo(u3.z); a5 += bfhi(u3.z); a6 += bflo(u3.w); a7 += bfhi(u3.w);
  }
  for (; e < e1; ++e) {
    const int s = csr[e];
    const uint4 u = hbf[(size_t)s * L + lane];
    a0 += bflo(u.x); a1 += bfhi(u.x); a2 += bflo(u.y); a3 += bfhi(u.y);
    a4 += bflo(u.z); a5 += bfhi(u.z); a6 += bflo(u.w); a7 += bfhi(u.w);
  }

  agg[(size_t)gid * L + lane] = make_uint4(packbf(a0, a1), packbf(a2, a3),
                                           packbf(a4, a5), packbf(a6, a7));
}

// ---------------------------------------------------------------------------
// MFMA fused MLP: out = relu(A@W1 + b1) @ W2 + b2.  (see R8 comments)
// ---------------------------------------------------------------------------
template <int K1, int NT2, bool OUTBF>
__global__ __launch_bounds__(256) void mlp_mfma_kernel(
    const short8* __restrict__ Abf, const short8* __restrict__ wf1,
    const float* __restrict__ b1, const short8* __restrict__ wf2,
    const float* __restrict__ b2, void* __restrict__ out, int n) {
  constexpr int KB1 = K1 / 32;
  __shared__ unsigned short zs[128 * 72];
  const int tid = threadIdx.x;
  const int lane = tid & 63;
  const int wid = tid >> 6;
  const int n0 = blockIdx.x * 128;
  const int l15 = lane & 15, lh = lane >> 4;

  // ---- GEMM1 ----
  short8 bf1[KB1 * 4];
#pragma unroll
  for (int f = 0; f < KB1 * 4; f++) bf1[f] = wf1[f * 64 + lane];

  f32x4 acc[2][4];
#pragma unroll
  for (int m = 0; m < 2; m++)
#pragma unroll
    for (int t = 0; t < 4; t++) acc[m][t] = (f32x4){0.f, 0.f, 0.f, 0.f};

#pragma unroll
  for (int m = 0; m < 2; m++) {
    const int row = n0 + wid * 32 + m * 16 + l15;
#pragma unroll
    for (int kb = 0; kb < KB1; kb++) {
      short8 a = {};
      if (row < n) a = Abf[(size_t)row * (K1 / 8) + kb * 4 + lh];
#pragma unroll
      for (int t = 0; t < 4; t++)
        acc[m][t] = __builtin_amdgcn_mfma_f32_16x16x32_bf16(a, bf1[kb * 4 + t],
                                                            acc[m][t], 0, 0, 0);
    }
  }

  // bias + relu + stage z (bf16)
  float b1v[4];
#pragma unroll
  for (int t = 0; t < 4; t++) b1v[t] = b1[t * 16 + l15];
#pragma unroll
  for (int m = 0; m < 2; m++)
#pragma unroll
    for (int t = 0; t < 4; t++)
#pragma unroll
      for (int r = 0; r < 4; r++) {
        const float z = fmaxf(acc[m][t][r] + b1v[t], 0.f);
        zs[(wid * 32 + m * 16 + lh * 4 + r) * 72 + t * 16 + l15] =
            (unsigned short)bfbits(z);
      }
  __syncthreads();

  // ---- GEMM2 (K=64) ----
  constexpr int NF2 = 2 * NT2;
  short8 bf2[NF2];
#pragma unroll
  for (int f = 0; f < NF2; f++) bf2[f] = wf2[f * 64 + lane];

  f32x4 acc2[2][NT2];
#pragma unroll
  for (int m = 0; m < 2; m++)
#pragma unroll
    for (int t = 0; t < NT2; t++) acc2[m][t] = (f32x4){0.f, 0.f, 0.f, 0.f};

#pragma unroll
  for (int m = 0; m < 2; m++) {
#pragma unroll
    for (int kb = 0; kb < 2; kb++) {
      const short8 a2 = *(const short8*)&zs[(wid * 32 + m * 16 + l15) * 72 +
                                            kb * 32 + lh * 8];
#pragma unroll
      for (int t = 0; t < NT2; t++)
        acc2[m][t] = __builtin_amdgcn_mfma_f32_16x16x32_bf16(
            a2, bf2[kb * NT2 + t], acc2[m][t], 0, 0, 0);
    }
  }
  __syncthreads();

  // ---- epilogue ----
  if (OUTBF) {
#pragma unroll
    for (int m = 0; m < 2; m++)
#pragma unroll
      for (int t = 0; t < 4; t++) {
        const float bb = b2[t * 16 + l15];
#pragma unroll
        for (int r = 0; r < 4; r++)
          zs[(wid * 32 + m * 16 + lh * 4 + r) * 72 + t * 16 + l15] =
              (unsigned short)bfbits(acc2[m][t][r] + bb);
      }
    __syncthreads();
    for (int i = tid; i < 128 * 8; i += 256) {
      const int row = i >> 3, q = i & 7;
      if (n0 + row < n)
        ((short8*)out)[(size_t)(n0 + row) * 8 + q] =
            *(const short8*)&zs[row * 72 + q * 8];
    }
  } else {
    float* zf = (float*)zs;  // [128][20] f32
    const float bb = b2[l15];
#pragma unroll
    for (int m = 0; m < 2; m++)
#pragma unroll
      for (int r = 0; r < 4; r++)
        zf[(wid * 32 + m * 16 + lh * 4 + r) * 20 + l15] = acc2[m][0][r] + bb;
    __syncthreads();
    for (int i = tid; i < 512; i += 256) {
      const int row = i >> 2, q = i & 3;
      if (n0 + row < n)
        ((float4*)out)[(size_t)(n0 + row) * 4 + q] =
            *(const float4*)&zf[row * 20 + q * 4];
    }
  }
}

extern "C" void kernel_launch(void* const* d_in, const int* in_sizes, int n_in,
                              void* d_out, int out_size, void* d_ws,
                              size_t ws_size, hipStream_t stream) {
  const float* x = (const float*)d_in[0];
  const int* ei = (const int*)d_in[1];
  const float* w1_0 = (const float*)d_in[2];
  const float* b1_0 = (const float*)d_in[3];
  const float* w2_0 = (const float*)d_in[4];
  const float* b2_0 = (const float*)d_in[5];
  const float* w1_1 = (const float*)d_in[6];
  const float* b1_1 = (const float*)d_in[7];
  const float* w2_1 = (const float*)d_in[8];
  const float* b2_1 = (const float*)d_in[9];
  const float* cw1 = (const float*)d_in[10];
  const float* cb1 = (const float*)d_in[11];
  const float* cw2 = (const float*)d_in[12];
  const float* cb2 = (const float*)d_in[13];

  const int n = in_sizes[0] / 32;  // nodes (< 2^17 for packing)
  const int ne = in_sizes[1] / 2;  // edges
  const int* src = ei;
  const int* dst = ei + ne;
  const int nb = (n + NPB - 1) / NPB;

  // Workspace layout (16B-aligned uint4 region first, then ints)
  uint4* aggbf = (uint4*)d_ws;                 // n*8  (bf16 [n][<=64])
  uint4* h0bf = aggbf + (size_t)n * 8;         // n*8  (bf16 [n][64])
  uint4* h1bf = h0bf + (size_t)n * 8;          // n*8  (bf16 [n][64])
  uint4* xbf = h1bf + (size_t)n * 8;           // n*4  (bf16 [n][32])
  uint4* wfrag = xbf + (size_t)n * 4;          // 38*64
  int* sorted = (int*)(wfrag + 38 * 64);       // ne
  int* csr = sorted + ne;                      // ne
  int* off = csr + ne;                         // n+1
  int* bcnt = off + n + 1;                     // nb
  int* boff = bcnt + nb;                       // nb+1
  int* bcur = boff + nb + 1;                   // nb

  // --- CSR build ---
  zero_kernel<<<1, 256, 0, stream>>>(bcnt, nb);
  bucket_hist_kernel<<<220, 256, 0, stream>>>(dst, bcnt, ne, nb);
  bucket_scan_kernel<<<1, 512, 0, stream>>>(bcnt, boff, bcur, nb, ne);
  partition_kernel<<<(ne + CHUNK - 1) / CHUNK, 256, 0, stream>>>(
      src, dst, bcur, sorted, ne, nb);
  fill_bucket_kernel<<<nb, 256, 0, stream>>>(sorted, boff, off, csr, n, ne);

  // x -> bf16 + weight repack (one launch)
  {
    const int n4 = n * 8;
    prep_kernel<<<1 + (n4 + 255) / 256, 256, 0, stream>>>(
        (const float4*)x, (uint2*)xbf, n4, w1_0, w2_0, w1_1, w2_1, cw1, cw2,
        wfrag);
  }

  const int ntile = (n + 127) / 128;
  const short8* wf = (const short8*)wfrag;

  // --- Layer 0 ---
  gather2_kernel<4><<<((size_t)n * 4 + 255) / 256, 256, 0, stream>>>(
      xbf, off, csr, aggbf, n);
  mlp_mfma_kernel<32, 4, true><<<ntile, 256, 0, stream>>>(
      (const short8*)aggbf, wf + 0 * 64, b1_0, wf + 4 * 64, b2_0, h0bf, n);

  // --- Layer 1 ---
  gather2_kernel<8><<<((size_t)n * 8 + 255) / 256, 256, 0, stream>>>(
      h0bf, off, csr, aggbf, n);
  mlp_mfma_kernel<64, 4, true><<<ntile, 256, 0, stream>>>(
      (const short8*)aggbf, wf + 12 * 64, b1_1, wf + 20 * 64, b2_1, h1bf, n);

  // --- Classifier ---
  mlp_mfma_kernel<64, 1, false><<<ntile, 256, 0, stream>>>(
      (const short8*)h1bf, wf + 28 * 64, cb1, wf + 36 * 64, cb2, d_out, n);
}

// Round 12
// 145.401 us; speedup vs baseline: 8.0157x; 1.0107x over previous
//
#include <hip/hip_runtime.h>

// ---------------------------------------------------------------------------
// TreeConv GNN. R11: R10's fused layers + barriers restored.
//   R10 raced: type-punned LDS (uint4 writes / short8 reads) with no
//   __syncthreads() lets the compiler reorder ds ops (no-alias assumption),
//   and stage N+1 overwrites LDS that stage N is still reading (WAR).
//   Fix: __syncthreads() after EVERY LDS phase. Structure unchanged:
//   fused0: gather(xbf) -> GEMM(w1_0)+relu -> GEMM(w2_0) -> h0bf
//   fused1: gather(h0bf) -> GEMM(w1_1)+relu -> GEMM(w2_1) -> GEMM(cw1)+relu
//           -> GEMM(cw2,N=16) -> out f32.   7 launches total.
// ---------------------------------------------------------------------------

#define NPB 256       // nodes per bucket; bucket id = dst >> 8
#define NBMAX 512     // max buckets (n <= 131072)
#define CHUNK 8192    // edges per partition block

typedef __attribute__((ext_vector_type(8))) short short8;
typedef __attribute__((ext_vector_type(4))) float f32x4;

__device__ inline unsigned int bfbits(float f) {  // RNE f32 -> bf16 bits
  unsigned int x = __float_as_uint(f);
  return (x + 0x7fffu + ((x >> 16) & 1u)) >> 16;
}
__device__ inline unsigned int packbf(float a, float b) {
  return bfbits(a) | (bfbits(b) << 16);
}
__device__ inline float bflo(unsigned int u) {
  return __uint_as_float(u << 16);
}
__device__ inline float bfhi(unsigned int u) {
  return __uint_as_float(u & 0xffff0000u);
}

// ---------------- CSR build ----------------

__global__ __launch_bounds__(256) void bucket_hist_kernel(
    const int* __restrict__ dst, int* __restrict__ bcnt, int ne, int nb) {
  __shared__ int h[NBMAX];
  for (int i = threadIdx.x; i < nb; i += 256) h[i] = 0;
  __syncthreads();
  for (int e = blockIdx.x * 256 + threadIdx.x; e < ne; e += gridDim.x * 256)
    atomicAdd(&h[dst[e] >> 8], 1);
  __syncthreads();
  for (int i = threadIdx.x; i < nb; i += 256) {
    const int c = h[i];
    if (c) atomicAdd(&bcnt[i], c);
  }
}

__global__ __launch_bounds__(512) void bucket_scan_kernel(
    const int* __restrict__ bcnt, int* __restrict__ boff,
    int* __restrict__ bcur, int nb, int ne) {
  __shared__ int wsum[8];
  const int lane = threadIdx.x & 63;
  const int wid = threadIdx.x >> 6;
  const int v = (threadIdx.x < nb) ? bcnt[threadIdx.x] : 0;
  int x = v;
#pragma unroll
  for (int s = 1; s < 64; s <<= 1) {
    int t = __shfl_up(x, s, 64);
    if (lane >= s) x += t;
  }
  if (lane == 63) wsum[wid] = x;
  __syncthreads();
  if (wid == 0 && lane < 8) {
    int y = wsum[lane];
#pragma unroll
    for (int s = 1; s < 8; s <<= 1) {
      int t = __shfl_up(y, s, 64);
      if (lane >= s) y += t;
    }
    wsum[lane] = y;
  }
  __syncthreads();
  const int wbase = (wid == 0) ? 0 : wsum[wid - 1];
  const int excl = wbase + x - v;
  if (threadIdx.x < nb) {
    boff[threadIdx.x] = excl;
    bcur[threadIdx.x] = excl;
  }
  if (threadIdx.x == 0) boff[nb] = ne;
}

__global__ __launch_bounds__(256) void partition_kernel(
    const int* __restrict__ src, const int* __restrict__ dst,
    int* __restrict__ bcur, int* __restrict__ sorted, int ne, int nb) {
  __shared__ int hist[NBMAX];
  __shared__ int lbase[NBMAX];
  __shared__ int gbase[NBMAX];
  __shared__ int cur[NBMAX];
  __shared__ int vals[CHUNK];
  __shared__ unsigned short bins[CHUNK];

  const int tid = threadIdx.x;
  const int e0 = blockIdx.x * CHUNK;
  const int m = min(CHUNK, ne - e0);

  for (int i = tid; i < nb; i += 256) hist[i] = 0;
  __syncthreads();
  for (int i = tid; i < m; i += 256) atomicAdd(&hist[dst[e0 + i] >> 8], 1);
  __syncthreads();

  if (tid < 64) {
    int v8[8];
    int tot = 0;
#pragma unroll
    for (int k = 0; k < 8; k++) {
      const int b = tid * 8 + k;
      v8[k] = (b < nb) ? hist[b] : 0;
      tot += v8[k];
    }
    int x = tot;
#pragma unroll
    for (int s = 1; s < 64; s <<= 1) {
      int t = __shfl_up(x, s, 64);
      if ((tid & 63) >= s) x += t;
    }
    int run = x - tot;
#pragma unroll
    for (int k = 0; k < 8; k++) {
      const int b = tid * 8 + k;
      if (b < nb) {
        lbase[b] = run;
        run += v8[k];
      }
    }
  }
  __syncthreads();

  for (int b = tid; b < nb; b += 256) {
    const int c = hist[b];
    cur[b] = lbase[b];
    gbase[b] = c ? atomicAdd(&bcur[b], c) : 0;
  }
  __syncthreads();

  for (int i = tid; i < m; i += 256) {
    const int s = src[e0 + i];
    const int d = dst[e0 + i];
    const int b = d >> 8;
    const int p = atomicAdd(&cur[b], 1);
    vals[p] = s | ((d & 255) << 17);
    bins[p] = (unsigned short)b;
  }
  __syncthreads();

  for (int i = tid; i < m; i += 256) {
    const int b = bins[i];
    sorted[gbase[b] + (i - lbase[b])] = vals[i];
  }
}

__global__ __launch_bounds__(256) void fill_bucket_kernel(
    const int* __restrict__ sorted, const int* __restrict__ boff,
    int* __restrict__ off, int* __restrict__ csr, int n, int ne) {
  __shared__ int hist[NPB];
  __shared__ int cur[NPB];
  __shared__ int wsum[4];
  const int tid = threadIdx.x;
  const int b = blockIdx.x;
  const int e0 = boff[b];
  const int m = boff[b + 1] - e0;

  hist[tid] = 0;
  __syncthreads();
  for (int i = tid; i < m; i += 256) atomicAdd(&hist[sorted[e0 + i] >> 17], 1);
  __syncthreads();

  const int lane = tid & 63;
  const int wid = tid >> 6;
  const int v = hist[tid];
  int x = v;
#pragma unroll
  for (int s = 1; s < 64; s <<= 1) {
    int t = __shfl_up(x, s, 64);
    if (lane >= s) x += t;
  }
  if (lane == 63) wsum[wid] = x;
  __syncthreads();
  if (tid == 0) {
    int s = 0;
#pragma unroll
    for (int k = 0; k < 4; k++) {
      const int t = wsum[k];
      wsum[k] = s;
      s += t;
    }
  }
  __syncthreads();
  const int excl = wsum[wid] + x - v;
  cur[tid] = excl;
  const int node = b * NPB + tid;
  if (node < n) off[node] = e0 + excl;
  if (b == 0 && tid == 0) off[n] = ne;
  __syncthreads();

  for (int i = tid; i < m; i += 256) {
    const int pv = sorted[e0 + i];
    const int r = atomicAdd(&cur[pv >> 17], 1);
    csr[e0 + r] = pv & 0x1FFFF;
  }
}

// ---------------------------------------------------------------------------
// prep: block 0 -> weight repack + zero bcnt; blocks 1.. -> x to bf16.
// Frag f, lane l holds W[kb*32+(l>>4)*8+i][t*16+(l&15)], i=0..7.
// wfrag: [0,4)=W1_0 [4,12)=W2_0 [12,20)=W1_1 [20,28)=W2_1 [28,36)=CW1
// [36,38)=CW2(N=16).
// ---------------------------------------------------------------------------
__global__ __launch_bounds__(256) void prep_kernel(
    const float4* __restrict__ x, uint2* __restrict__ xbf, int n4,
    const float* __restrict__ w1_0, const float* __restrict__ w2_0,
    const float* __restrict__ w1_1, const float* __restrict__ w2_1,
    const float* __restrict__ cw1, const float* __restrict__ cw2,
    uint4* __restrict__ wfrag, int* __restrict__ bcnt, int nb) {
  if (blockIdx.x == 0) {
    for (int i = threadIdx.x; i < nb; i += 256) bcnt[i] = 0;
    for (int idx = threadIdx.x; idx < 38 * 64; idx += 256) {
      const int f = idx >> 6, l = idx & 63;
      const float* W;
      int N = 64, f0;
      if (f < 4) { W = w1_0; f0 = f; }
      else if (f < 12) { W = w2_0; f0 = f - 4; }
      else if (f < 20) { W = w1_1; f0 = f - 12; }
      else if (f < 28) { W = w2_1; f0 = f - 20; }
      else if (f < 36) { W = cw1; f0 = f - 28; }
      else { W = cw2; f0 = f - 36; N = 16; }
      int kb, t;
      if (N == 16) { kb = f0; t = 0; } else { kb = f0 >> 2; t = f0 & 3; }
      const int k0 = kb * 32 + (l >> 4) * 8;
      const int col = t * 16 + (l & 15);
      unsigned int p[4];
#pragma unroll
      for (int j = 0; j < 4; j++)
        p[j] =
            packbf(W[(k0 + 2 * j) * N + col], W[(k0 + 2 * j + 1) * N + col]);
      wfrag[idx] = make_uint4(p[0], p[1], p[2], p[3]);
    }
    return;
  }
  const int i = (blockIdx.x - 1) * 256 + threadIdx.x;
  if (i < n4) {
    const float4 v = x[i];
    xbf[i] = make_uint2(packbf(v.x, v.y), packbf(v.z, v.w));
  }
}

// ---------------------------------------------------------------------------
// Per-wave GEMM stage on LDS tiles. Caller must __syncthreads() between
// stages (compiler memory fence + cross-stage WAR safety).
// ---------------------------------------------------------------------------
template <int KB, int NT, bool RELU>
__device__ inline void gemm_stage(const unsigned short* __restrict__ src,
                                  int srcs, unsigned short* __restrict__ dst,
                                  const short8* __restrict__ wfrag,
                                  const float* __restrict__ bias, int wid,
                                  int lane) {
  const int l15 = lane & 15, lh = lane >> 4;
  short8 bf[KB * NT];
#pragma unroll
  for (int f = 0; f < KB * NT; f++) bf[f] = wfrag[f * 64 + lane];
  f32x4 acc[2][NT];
#pragma unroll
  for (int m = 0; m < 2; m++)
#pragma unroll
    for (int t = 0; t < NT; t++) acc[m][t] = (f32x4){0.f, 0.f, 0.f, 0.f};
#pragma unroll
  for (int m = 0; m < 2; m++)
#pragma unroll
    for (int kb = 0; kb < KB; kb++) {
      const short8 a = *(const short8*)&src[(wid * 32 + m * 16 + l15) * srcs +
                                            kb * 32 + lh * 8];
#pragma unroll
      for (int t = 0; t < NT; t++)
        acc[m][t] = __builtin_amdgcn_mfma_f32_16x16x32_bf16(a, bf[kb * NT + t],
                                                            acc[m][t], 0, 0, 0);
    }
  float bv[NT];
#pragma unroll
  for (int t = 0; t < NT; t++) bv[t] = bias[t * 16 + l15];
#pragma unroll
  for (int m = 0; m < 2; m++)
#pragma unroll
    for (int t = 0; t < NT; t++)
#pragma unroll
      for (int r = 0; r < 4; r++) {
        float v = acc[m][t][r] + bv[t];
        if (RELU) v = fmaxf(v, 0.f);
        dst[(wid * 32 + m * 16 + lh * 4 + r) * 72 + t * 16 + l15] =
            (unsigned short)bfbits(v);
      }
}

// ---------------------------------------------------------------------------
// fused0: gather(xbf, D=32) -> GEMM(w1_0)+relu -> GEMM(w2_0) -> h0bf.
// ---------------------------------------------------------------------------
__global__ __launch_bounds__(256) void fused0_kernel(
    const uint4* __restrict__ xbf, const int* __restrict__ off,
    const int* __restrict__ csr, const short8* __restrict__ wf,
    const float* __restrict__ b1, const float* __restrict__ b2,
    uint4* __restrict__ h0bf, int n) {
  __shared__ unsigned short zsA[128 * 72];
  __shared__ unsigned short zsB[128 * 72];
  const int tid = threadIdx.x;
  const int lane = tid & 63;
  const int wid = tid >> 6;
  const int n0 = blockIdx.x * 128;

  // gather: node = tid>>1, half = tid&1 owns 2 uint4 (16 bf16)
  {
    const int node = tid >> 1;
    const int half = tid & 1;
    const int g = n0 + node;
    float a[16];
#pragma unroll
    for (int i = 0; i < 16; i++) a[i] = 0.f;
    if (g < n) {
      const uint4* base = xbf + (size_t)g * 4 + half * 2;
      uint4 u0 = base[0], u1 = base[1];
      a[0] = bflo(u0.x); a[1] = bfhi(u0.x); a[2] = bflo(u0.y); a[3] = bfhi(u0.y);
      a[4] = bflo(u0.z); a[5] = bfhi(u0.z); a[6] = bflo(u0.w); a[7] = bfhi(u0.w);
      a[8] = bflo(u1.x); a[9] = bfhi(u1.x); a[10] = bflo(u1.y); a[11] = bfhi(u1.y);
      a[12] = bflo(u1.z); a[13] = bfhi(u1.z); a[14] = bflo(u1.w); a[15] = bfhi(u1.w);
      const int e0 = off[g], e1 = off[g + 1];
      int e = e0;
      for (; e + 3 < e1; e += 4) {
        const int s0 = csr[e], s1 = csr[e + 1], s2 = csr[e + 2],
                  s3 = csr[e + 3];
        uint4 v0[2], v1[2], v2[2], v3[2];
        const uint4* p0 = xbf + (size_t)s0 * 4 + half * 2;
        const uint4* p1 = xbf + (size_t)s1 * 4 + half * 2;
        const uint4* p2 = xbf + (size_t)s2 * 4 + half * 2;
        const uint4* p3 = xbf + (size_t)s3 * 4 + half * 2;
        v0[0] = p0[0]; v0[1] = p0[1]; v1[0] = p1[0]; v1[1] = p1[1];
        v2[0] = p2[0]; v2[1] = p2[1]; v3[0] = p3[0]; v3[1] = p3[1];
#pragma unroll
        for (int q = 0; q < 2; q++) {
          a[q * 8 + 0] += bflo(v0[q].x) + bflo(v1[q].x) + bflo(v2[q].x) + bflo(v3[q].x);
          a[q * 8 + 1] += bfhi(v0[q].x) + bfhi(v1[q].x) + bfhi(v2[q].x) + bfhi(v3[q].x);
          a[q * 8 + 2] += bflo(v0[q].y) + bflo(v1[q].y) + bflo(v2[q].y) + bflo(v3[q].y);
          a[q * 8 + 3] += bfhi(v0[q].y) + bfhi(v1[q].y) + bfhi(v2[q].y) + bfhi(v3[q].y);
          a[q * 8 + 4] += bflo(v0[q].z) + bflo(v1[q].z) + bflo(v2[q].z) + bflo(v3[q].z);
          a[q * 8 + 5] += bfhi(v0[q].z) + bfhi(v1[q].z) + bfhi(v2[q].z) + bfhi(v3[q].z);
          a[q * 8 + 6] += bflo(v0[q].w) + bflo(v1[q].w) + bflo(v2[q].w) + bflo(v3[q].w);
          a[q * 8 + 7] += bfhi(v0[q].w) + bfhi(v1[q].w) + bfhi(v2[q].w) + bfhi(v3[q].w);
        }
      }
      for (; e < e1; ++e) {
        const uint4* p = xbf + (size_t)csr[e] * 4 + half * 2;
        uint4 w0 = p[0], w1 = p[1];
        a[0] += bflo(w0.x); a[1] += bfhi(w0.x); a[2] += bflo(w0.y); a[3] += bfhi(w0.y);
        a[4] += bflo(w0.z); a[5] += bfhi(w0.z); a[6] += bflo(w0.w); a[7] += bfhi(w0.w);
        a[8] += bflo(w1.x); a[9] += bfhi(w1.x); a[10] += bflo(w1.y); a[11] += bfhi(w1.y);
        a[12] += bflo(w1.z); a[13] += bfhi(w1.z); a[14] += bflo(w1.w); a[15] += bfhi(w1.w);
      }
    }
    // stage agg bf16 -> zsA [128][40]
#pragma unroll
    for (int q = 0; q < 2; q++) {
      uint4 w;
      w.x = packbf(a[q * 8 + 0], a[q * 8 + 1]);
      w.y = packbf(a[q * 8 + 2], a[q * 8 + 3]);
      w.z = packbf(a[q * 8 + 4], a[q * 8 + 5]);
      w.w = packbf(a[q * 8 + 6], a[q * 8 + 7]);
      *(uint4*)&zsA[node * 40 + half * 16 + q * 8] = w;
    }
  }
  __syncthreads();
  gemm_stage<1, 4, true>(zsA, 40, zsB, wf + 0 * 64, b1, wid, lane);
  __syncthreads();
  gemm_stage<2, 4, false>(zsB, 72, zsA, wf + 4 * 64, b2, wid, lane);
  __syncthreads();

  for (int i = tid; i < 128 * 8; i += 256) {
    const int row = i >> 3, q = i & 7;
    if (n0 + row < n)
      ((short8*)h0bf)[(size_t)(n0 + row) * 8 + q] =
          *(const short8*)&zsA[row * 72 + q * 8];
  }
}

// ---------------------------------------------------------------------------
// fused1: gather(h0bf, D=64) -> GEMM(w1_1)+relu -> GEMM(w2_1) -> GEMM(cw1)
// +relu -> GEMM(cw2, N=16) -> out f32.
// ---------------------------------------------------------------------------
__global__ __launch_bounds__(256) void fused1_kernel(
    const uint4* __restrict__ hbf, const int* __restrict__ off,
    const int* __restrict__ csr, const short8* __restrict__ wf,
    const float* __restrict__ b1, const float* __restrict__ b2,
    const float* __restrict__ cb1, const float* __restrict__ cb2,
    float* __restrict__ out, int n) {
  __shared__ unsigned short zsA[128 * 72];
  __shared__ unsigned short zsB[128 * 72];
  const int tid = threadIdx.x;
  const int lane = tid & 63;
  const int wid = tid >> 6;
  const int n0 = blockIdx.x * 128;
  const int l15 = lane & 15, lh = lane >> 4;

  // gather: node = tid>>1, half = tid&1 owns 4 uint4 (32 bf16)
  {
    const int node = tid >> 1;
    const int half = tid & 1;
    const int g = n0 + node;
    float a[32];
#pragma unroll
    for (int i = 0; i < 32; i++) a[i] = 0.f;
    if (g < n) {
      const uint4* base = hbf + (size_t)g * 8 + half * 4;
      uint4 u[4];
#pragma unroll
      for (int q = 0; q < 4; q++) u[q] = base[q];
#pragma unroll
      for (int q = 0; q < 4; q++) {
        a[q * 8 + 0] = bflo(u[q].x); a[q * 8 + 1] = bfhi(u[q].x);
        a[q * 8 + 2] = bflo(u[q].y); a[q * 8 + 3] = bfhi(u[q].y);
        a[q * 8 + 4] = bflo(u[q].z); a[q * 8 + 5] = bfhi(u[q].z);
        a[q * 8 + 6] = bflo(u[q].w); a[q * 8 + 7] = bfhi(u[q].w);
      }
      const int e0 = off[g], e1 = off[g + 1];
      int e = e0;
      for (; e + 1 < e1; e += 2) {
        const int s0 = csr[e], s1 = csr[e + 1];
        const uint4* p0 = hbf + (size_t)s0 * 8 + half * 4;
        const uint4* p1 = hbf + (size_t)s1 * 8 + half * 4;
        uint4 v0[4], v1[4];
#pragma unroll
        for (int q = 0; q < 4; q++) v0[q] = p0[q];
#pragma unroll
        for (int q = 0; q < 4; q++) v1[q] = p1[q];
#pragma unroll
        for (int q = 0; q < 4; q++) {
          a[q * 8 + 0] += bflo(v0[q].x) + bflo(v1[q].x);
          a[q * 8 + 1] += bfhi(v0[q].x) + bfhi(v1[q].x);
          a[q * 8 + 2] += bflo(v0[q].y) + bflo(v1[q].y);
          a[q * 8 + 3] += bfhi(v0[q].y) + bfhi(v1[q].y);
          a[q * 8 + 4] += bflo(v0[q].z) + bflo(v1[q].z);
          a[q * 8 + 5] += bfhi(v0[q].z) + bfhi(v1[q].z);
          a[q * 8 + 6] += bflo(v0[q].w) + bflo(v1[q].w);
          a[q * 8 + 7] += bfhi(v0[q].w) + bfhi(v1[q].w);
        }
      }
      if (e < e1) {
        const uint4* p = hbf + (size_t)csr[e] * 8 + half * 4;
#pragma unroll
        for (int q = 0; q < 4; q++) {
          const uint4 w = p[q];
          a[q * 8 + 0] += bflo(w.x); a[q * 8 + 1] += bfhi(w.x);
          a[q * 8 + 2] += bflo(w.y); a[q * 8 + 3] += bfhi(w.y);
          a[q * 8 + 4] += bflo(w.z); a[q * 8 + 5] += bfhi(w.z);
          a[q * 8 + 6] += bflo(w.w); a[q * 8 + 7] += bfhi(w.w);
        }
      }
    }
#pragma unroll
    for (int q = 0; q < 4; q++) {
      uint4 w;
      w.x = packbf(a[q * 8 + 0], a[q * 8 + 1]);
      w.y = packbf(a[q * 8 + 2], a[q * 8 + 3]);
      w.z = packbf(a[q * 8 + 4], a[q * 8 + 5]);
      w.w = packbf(a[q * 8 + 6], a[q * 8 + 7]);
      *(uint4*)&zsA[node * 72 + half * 32 + q * 8] = w;
    }
  }
  __syncthreads();
  gemm_stage<2, 4, true>(zsA, 72, zsB, wf + 12 * 64, b1, wid, lane);   // z1
  __syncthreads();
  gemm_stage<2, 4, false>(zsB, 72, zsA, wf + 20 * 64, b2, wid, lane);  // h1
  __syncthreads();
  gemm_stage<2, 4, true>(zsA, 72, zsB, wf + 28 * 64, cb1, wid, lane);  // z2
  __syncthreads();

  // GEMM4: K=64, N=16 (cw2) -> f32 out
  {
    short8 bf0 = wf[36 * 64 + lane];
    short8 bf1 = wf[37 * 64 + lane];
    f32x4 acc[2];
#pragma unroll
    for (int m = 0; m < 2; m++) acc[m] = (f32x4){0.f, 0.f, 0.f, 0.f};
#pragma unroll
    for (int m = 0; m < 2; m++) {
#pragma unroll
      for (int kb = 0; kb < 2; kb++) {
        const short8 a = *(const short8*)&zsB[(wid * 32 + m * 16 + l15) * 72 +
                                              kb * 32 + lh * 8];
        acc[m] = __builtin_amdgcn_mfma_f32_16x16x32_bf16(
            a, kb ? bf1 : bf0, acc[m], 0, 0, 0);
      }
    }
    __syncthreads();  // all z2 reads of zsA done before zf overwrite
    float* zf = (float*)zsA;  // [128][20] f32
    const float bb = cb2[l15];
#pragma unroll
    for (int m = 0; m < 2; m++)
#pragma unroll
      for (int r = 0; r < 4; r++)
        zf[(wid * 32 + m * 16 + lh * 4 + r) * 20 + l15] = acc[m][r] + bb;
    __syncthreads();
    for (int i = tid; i < 512; i += 256) {
      const int row = i >> 2, q = i & 3;
      if (n0 + row < n)
        ((float4*)out)[(size_t)(n0 + row) * 4 + q] =
            *(const float4*)&zf[row * 20 + q * 4];
    }
  }
}

extern "C" void kernel_launch(void* const* d_in, const int* in_sizes, int n_in,
                              void* d_out, int out_size, void* d_ws,
                              size_t ws_size, hipStream_t stream) {
  const float* x = (const float*)d_in[0];
  const int* ei = (const int*)d_in[1];
  const float* w1_0 = (const float*)d_in[2];
  const float* b1_0 = (const float*)d_in[3];
  const float* w2_0 = (const float*)d_in[4];
  const float* b2_0 = (const float*)d_in[5];
  const float* w1_1 = (const float*)d_in[6];
  const float* b1_1 = (const float*)d_in[7];
  const float* w2_1 = (const float*)d_in[8];
  const float* b2_1 = (const float*)d_in[9];
  const float* cw1 = (const float*)d_in[10];
  const float* cb1 = (const float*)d_in[11];
  const float* cw2 = (const float*)d_in[12];
  const float* cb2 = (const float*)d_in[13];

  const int n = in_sizes[0] / 32;  // nodes (< 2^17 for packing)
  const int ne = in_sizes[1] / 2;  // edges
  const int* src = ei;
  const int* dst = ei + ne;
  const int nb = (n + NPB - 1) / NPB;

  // Workspace layout (16B-aligned uint4 region first, then ints)
  uint4* h0bf = (uint4*)d_ws;                  // n*8  (bf16 [n][64])
  uint4* xbf = h0bf + (size_t)n * 8;           // n*4  (bf16 [n][32])
  uint4* wfrag = xbf + (size_t)n * 4;          // 38*64
  int* sorted = (int*)(wfrag + 38 * 64);       // ne
  int* csr = sorted + ne;                      // ne
  int* off = csr + ne;                         // n+1
  int* bcnt = off + n + 1;                     // nb
  int* boff = bcnt + nb;                       // nb+1
  int* bcur = boff + nb + 1;                   // nb

  // prep first: zeroes bcnt, builds xbf + wfrag
  {
    const int n4 = n * 8;
    prep_kernel<<<1 + (n4 + 255) / 256, 256, 0, stream>>>(
        (const float4*)x, (uint2*)xbf, n4, w1_0, w2_0, w1_1, w2_1, cw1, cw2,
        wfrag, bcnt, nb);
  }

  // --- CSR build ---
  bucket_hist_kernel<<<220, 256, 0, stream>>>(dst, bcnt, ne, nb);
  bucket_scan_kernel<<<1, 512, 0, stream>>>(bcnt, boff, bcur, nb, ne);
  partition_kernel<<<(ne + CHUNK - 1) / CHUNK, 256, 0, stream>>>(
      src, dst, bcur, sorted, ne, nb);
  fill_bucket_kernel<<<nb, 256, 0, stream>>>(sorted, boff, off, csr, n, ne);

  const int ntile = (n + 127) / 128;
  const short8* wf = (const short8*)wfrag;

  fused0_kernel<<<ntile, 256, 0, stream>>>(xbf, off, csr, wf, b1_0, b2_0,
                                           h0bf, n);
  fused1_kernel<<<ntile, 256, 0, stream>>>(h0bf, off, csr, wf, b1_1, b2_1,
                                           cb1, cb2, (float*)d_out, n);
}

// Round 13
// 132.587 us; speedup vs baseline: 8.7904x; 1.0966x over previous
//
#include <hip/hip_runtime.h>

// ---------------------------------------------------------------------------
// TreeConv GNN. R12: 64-node tiles for the fused kernels.
//   R11 profile: fused1 = 55us, Occupancy 21% -> grid-limited (782 blocks =
//   3/CU) while the gather phase is latency-bound. Halve tile to 64 nodes:
//   1563 blocks, 4 threads/node, 4-deep edge unroll, 1 M-tile/wave MFMA,
//   LDS ~18KB. Everything else unchanged from R11 (barriers after every LDS
//   phase -- R10's race lesson).
// ---------------------------------------------------------------------------

#define NPB 256       // nodes per bucket; bucket id = dst >> 8
#define NBMAX 512     // max buckets (n <= 131072)
#define CHUNK 8192    // edges per partition block

typedef __attribute__((ext_vector_type(8))) short short8;
typedef __attribute__((ext_vector_type(4))) float f32x4;

__device__ inline unsigned int bfbits(float f) {  // RNE f32 -> bf16 bits
  unsigned int x = __float_as_uint(f);
  return (x + 0x7fffu + ((x >> 16) & 1u)) >> 16;
}
__device__ inline unsigned int packbf(float a, float b) {
  return bfbits(a) | (bfbits(b) << 16);
}
__device__ inline float bflo(unsigned int u) {
  return __uint_as_float(u << 16);
}
__device__ inline float bfhi(unsigned int u) {
  return __uint_as_float(u & 0xffff0000u);
}

// ---------------- CSR build ----------------

__global__ __launch_bounds__(256) void bucket_hist_kernel(
    const int* __restrict__ dst, int* __restrict__ bcnt, int ne, int nb) {
  __shared__ int h[NBMAX];
  for (int i = threadIdx.x; i < nb; i += 256) h[i] = 0;
  __syncthreads();
  for (int e = blockIdx.x * 256 + threadIdx.x; e < ne; e += gridDim.x * 256)
    atomicAdd(&h[dst[e] >> 8], 1);
  __syncthreads();
  for (int i = threadIdx.x; i < nb; i += 256) {
    const int c = h[i];
    if (c) atomicAdd(&bcnt[i], c);
  }
}

__global__ __launch_bounds__(512) void bucket_scan_kernel(
    const int* __restrict__ bcnt, int* __restrict__ boff,
    int* __restrict__ bcur, int nb, int ne) {
  __shared__ int wsum[8];
  const int lane = threadIdx.x & 63;
  const int wid = threadIdx.x >> 6;
  const int v = (threadIdx.x < nb) ? bcnt[threadIdx.x] : 0;
  int x = v;
#pragma unroll
  for (int s = 1; s < 64; s <<= 1) {
    int t = __shfl_up(x, s, 64);
    if (lane >= s) x += t;
  }
  if (lane == 63) wsum[wid] = x;
  __syncthreads();
  if (wid == 0 && lane < 8) {
    int y = wsum[lane];
#pragma unroll
    for (int s = 1; s < 8; s <<= 1) {
      int t = __shfl_up(y, s, 64);
      if (lane >= s) y += t;
    }
    wsum[lane] = y;
  }
  __syncthreads();
  const int wbase = (wid == 0) ? 0 : wsum[wid - 1];
  const int excl = wbase + x - v;
  if (threadIdx.x < nb) {
    boff[threadIdx.x] = excl;
    bcur[threadIdx.x] = excl;
  }
  if (threadIdx.x == 0) boff[nb] = ne;
}

__global__ __launch_bounds__(256) void partition_kernel(
    const int* __restrict__ src, const int* __restrict__ dst,
    int* __restrict__ bcur, int* __restrict__ sorted, int ne, int nb) {
  __shared__ int hist[NBMAX];
  __shared__ int lbase[NBMAX];
  __shared__ int gbase[NBMAX];
  __shared__ int cur[NBMAX];
  __shared__ int vals[CHUNK];
  __shared__ unsigned short bins[CHUNK];

  const int tid = threadIdx.x;
  const int e0 = blockIdx.x * CHUNK;
  const int m = min(CHUNK, ne - e0);

  for (int i = tid; i < nb; i += 256) hist[i] = 0;
  __syncthreads();
  for (int i = tid; i < m; i += 256) atomicAdd(&hist[dst[e0 + i] >> 8], 1);
  __syncthreads();

  if (tid < 64) {
    int v8[8];
    int tot = 0;
#pragma unroll
    for (int k = 0; k < 8; k++) {
      const int b = tid * 8 + k;
      v8[k] = (b < nb) ? hist[b] : 0;
      tot += v8[k];
    }
    int x = tot;
#pragma unroll
    for (int s = 1; s < 64; s <<= 1) {
      int t = __shfl_up(x, s, 64);
      if ((tid & 63) >= s) x += t;
    }
    int run = x - tot;
#pragma unroll
    for (int k = 0; k < 8; k++) {
      const int b = tid * 8 + k;
      if (b < nb) {
        lbase[b] = run;
        run += v8[k];
      }
    }
  }
  __syncthreads();

  for (int b = tid; b < nb; b += 256) {
    const int c = hist[b];
    cur[b] = lbase[b];
    gbase[b] = c ? atomicAdd(&bcur[b], c) : 0;
  }
  __syncthreads();

  for (int i = tid; i < m; i += 256) {
    const int s = src[e0 + i];
    const int d = dst[e0 + i];
    const int b = d >> 8;
    const int p = atomicAdd(&cur[b], 1);
    vals[p] = s | ((d & 255) << 17);
    bins[p] = (unsigned short)b;
  }
  __syncthreads();

  for (int i = tid; i < m; i += 256) {
    const int b = bins[i];
    sorted[gbase[b] + (i - lbase[b])] = vals[i];
  }
}

__global__ __launch_bounds__(256) void fill_bucket_kernel(
    const int* __restrict__ sorted, const int* __restrict__ boff,
    int* __restrict__ off, int* __restrict__ csr, int n, int ne) {
  __shared__ int hist[NPB];
  __shared__ int cur[NPB];
  __shared__ int wsum[4];
  const int tid = threadIdx.x;
  const int b = blockIdx.x;
  const int e0 = boff[b];
  const int m = boff[b + 1] - e0;

  hist[tid] = 0;
  __syncthreads();
  for (int i = tid; i < m; i += 256) atomicAdd(&hist[sorted[e0 + i] >> 17], 1);
  __syncthreads();

  const int lane = tid & 63;
  const int wid = tid >> 6;
  const int v = hist[tid];
  int x = v;
#pragma unroll
  for (int s = 1; s < 64; s <<= 1) {
    int t = __shfl_up(x, s, 64);
    if (lane >= s) x += t;
  }
  if (lane == 63) wsum[wid] = x;
  __syncthreads();
  if (tid == 0) {
    int s = 0;
#pragma unroll
    for (int k = 0; k < 4; k++) {
      const int t = wsum[k];
      wsum[k] = s;
      s += t;
    }
  }
  __syncthreads();
  const int excl = wsum[wid] + x - v;
  cur[tid] = excl;
  const int node = b * NPB + tid;
  if (node < n) off[node] = e0 + excl;
  if (b == 0 && tid == 0) off[n] = ne;
  __syncthreads();

  for (int i = tid; i < m; i += 256) {
    const int pv = sorted[e0 + i];
    const int r = atomicAdd(&cur[pv >> 17], 1);
    csr[e0 + r] = pv & 0x1FFFF;
  }
}

// ---------------------------------------------------------------------------
// prep: block 0 -> weight repack + zero bcnt; blocks 1.. -> x to bf16.
// wfrag: [0,4)=W1_0 [4,12)=W2_0 [12,20)=W1_1 [20,28)=W2_1 [28,36)=CW1
// [36,38)=CW2(N=16).
// ---------------------------------------------------------------------------
__global__ __launch_bounds__(256) void prep_kernel(
    const float4* __restrict__ x, uint2* __restrict__ xbf, int n4,
    const float* __restrict__ w1_0, const float* __restrict__ w2_0,
    const float* __restrict__ w1_1, const float* __restrict__ w2_1,
    const float* __restrict__ cw1, const float* __restrict__ cw2,
    uint4* __restrict__ wfrag, int* __restrict__ bcnt, int nb) {
  if (blockIdx.x == 0) {
    for (int i = threadIdx.x; i < nb; i += 256) bcnt[i] = 0;
    for (int idx = threadIdx.x; idx < 38 * 64; idx += 256) {
      const int f = idx >> 6, l = idx & 63;
      const float* W;
      int N = 64, f0;
      if (f < 4) { W = w1_0; f0 = f; }
      else if (f < 12) { W = w2_0; f0 = f - 4; }
      else if (f < 20) { W = w1_1; f0 = f - 12; }
      else if (f < 28) { W = w2_1; f0 = f - 20; }
      else if (f < 36) { W = cw1; f0 = f - 28; }
      else { W = cw2; f0 = f - 36; N = 16; }
      int kb, t;
      if (N == 16) { kb = f0; t = 0; } else { kb = f0 >> 2; t = f0 & 3; }
      const int k0 = kb * 32 + (l >> 4) * 8;
      const int col = t * 16 + (l & 15);
      unsigned int p[4];
#pragma unroll
      for (int j = 0; j < 4; j++)
        p[j] =
            packbf(W[(k0 + 2 * j) * N + col], W[(k0 + 2 * j + 1) * N + col]);
      wfrag[idx] = make_uint4(p[0], p[1], p[2], p[3]);
    }
    return;
  }
  const int i = (blockIdx.x - 1) * 256 + threadIdx.x;
  if (i < n4) {
    const float4 v = x[i];
    xbf[i] = make_uint2(packbf(v.x, v.y), packbf(v.z, v.w));
  }
}

// ---------------------------------------------------------------------------
// Per-wave GEMM stage on 64-row LDS tiles: wave wid owns rows
// [16*wid, 16*wid+16). Caller must __syncthreads() between stages.
// ---------------------------------------------------------------------------
template <int KB, int NT, bool RELU>
__device__ inline void gemm_stage(const unsigned short* __restrict__ src,
                                  int srcs, unsigned short* __restrict__ dst,
                                  const short8* __restrict__ wfrag,
                                  const float* __restrict__ bias, int wid,
                                  int lane) {
  const int l15 = lane & 15, lh = lane >> 4;
  short8 bf[KB * NT];
#pragma unroll
  for (int f = 0; f < KB * NT; f++) bf[f] = wfrag[f * 64 + lane];
  f32x4 acc[NT];
#pragma unroll
  for (int t = 0; t < NT; t++) acc[t] = (f32x4){0.f, 0.f, 0.f, 0.f};
#pragma unroll
  for (int kb = 0; kb < KB; kb++) {
    const short8 a =
        *(const short8*)&src[(wid * 16 + l15) * srcs + kb * 32 + lh * 8];
#pragma unroll
    for (int t = 0; t < NT; t++)
      acc[t] = __builtin_amdgcn_mfma_f32_16x16x32_bf16(a, bf[kb * NT + t],
                                                       acc[t], 0, 0, 0);
  }
  float bv[NT];
#pragma unroll
  for (int t = 0; t < NT; t++) bv[t] = bias[t * 16 + l15];
#pragma unroll
  for (int t = 0; t < NT; t++)
#pragma unroll
    for (int r = 0; r < 4; r++) {
      float v = acc[t][r] + bv[t];
      if (RELU) v = fmaxf(v, 0.f);
      dst[(wid * 16 + lh * 4 + r) * 72 + t * 16 + l15] =
          (unsigned short)bfbits(v);
    }
}

// ---------------------------------------------------------------------------
// fused0: gather(xbf, D=32) -> GEMM(w1_0)+relu -> GEMM(w2_0) -> h0bf.
// 64 nodes/block, 4 threads/node (1 uint4 = 8 bf16 each), 4-deep unroll.
// ---------------------------------------------------------------------------
__global__ __launch_bounds__(256) void fused0_kernel(
    const uint4* __restrict__ xbf, const int* __restrict__ off,
    const int* __restrict__ csr, const short8* __restrict__ wf,
    const float* __restrict__ b1, const float* __restrict__ b2,
    uint4* __restrict__ h0bf, int n) {
  __shared__ unsigned short zsA[64 * 40];
  __shared__ unsigned short zsB[64 * 72];
  const int tid = threadIdx.x;
  const int lane = tid & 63;
  const int wid = tid >> 6;
  const int n0 = blockIdx.x * 64;

  // gather: node = tid>>2, q4 = tid&3 owns uint4 #q4 of the row
  {
    const int node = tid >> 2;
    const int q4 = tid & 3;
    const int g = n0 + node;
    float a[8];
#pragma unroll
    for (int i = 0; i < 8; i++) a[i] = 0.f;
    if (g < n) {
      const uint4 u = xbf[(size_t)g * 4 + q4];
      a[0] = bflo(u.x); a[1] = bfhi(u.x); a[2] = bflo(u.y); a[3] = bfhi(u.y);
      a[4] = bflo(u.z); a[5] = bfhi(u.z); a[6] = bflo(u.w); a[7] = bfhi(u.w);
      const int e0 = off[g], e1 = off[g + 1];
      int e = e0;
      for (; e + 3 < e1; e += 4) {
        const int s0 = csr[e], s1 = csr[e + 1], s2 = csr[e + 2],
                  s3 = csr[e + 3];
        const uint4 u0 = xbf[(size_t)s0 * 4 + q4];
        const uint4 u1 = xbf[(size_t)s1 * 4 + q4];
        const uint4 u2 = xbf[(size_t)s2 * 4 + q4];
        const uint4 u3 = xbf[(size_t)s3 * 4 + q4];
        a[0] += bflo(u0.x) + bflo(u1.x) + bflo(u2.x) + bflo(u3.x);
        a[1] += bfhi(u0.x) + bfhi(u1.x) + bfhi(u2.x) + bfhi(u3.x);
        a[2] += bflo(u0.y) + bflo(u1.y) + bflo(u2.y) + bflo(u3.y);
        a[3] += bfhi(u0.y) + bfhi(u1.y) + bfhi(u2.y) + bfhi(u3.y);
        a[4] += bflo(u0.z) + bflo(u1.z) + bflo(u2.z) + bflo(u3.z);
        a[5] += bfhi(u0.z) + bfhi(u1.z) + bfhi(u2.z) + bfhi(u3.z);
        a[6] += bflo(u0.w) + bflo(u1.w) + bflo(u2.w) + bflo(u3.w);
        a[7] += bfhi(u0.w) + bfhi(u1.w) + bfhi(u2.w) + bfhi(u3.w);
      }
      for (; e < e1; ++e) {
        const uint4 u4 = xbf[(size_t)csr[e] * 4 + q4];
        a[0] += bflo(u4.x); a[1] += bfhi(u4.x);
        a[2] += bflo(u4.y); a[3] += bfhi(u4.y);
        a[4] += bflo(u4.z); a[5] += bfhi(u4.z);
        a[6] += bflo(u4.w); a[7] += bfhi(u4.w);
      }
    }
    uint4 w;
    w.x = packbf(a[0], a[1]); w.y = packbf(a[2], a[3]);
    w.z = packbf(a[4], a[5]); w.w = packbf(a[6], a[7]);
    *(uint4*)&zsA[node * 40 + q4 * 8] = w;
  }
  __syncthreads();
  gemm_stage<1, 4, true>(zsA, 40, zsB, wf + 0 * 64, b1, wid, lane);
  __syncthreads();
  gemm_stage<2, 4, false>(zsB, 72, (unsigned short*)zsA, wf + 4 * 64, b2, wid,
                          lane);
  __syncthreads();

  // zsA reused as [64][72] output staging? zsA is only 64*40 -- write from
  // zsB? No: stage2 wrote to zsA but zsA stride-72 rows need 64*72. Use zsB
  // as destination instead. (See launch note below.)
}

// Corrected fused0: stage2 writes back to zsB is impossible (src==dst).
// Use explicit big buffer: zsA [64*72] for both A-tile (stride 40 region
// fits inside) and final output; zsB [64*72] for z.
__global__ __launch_bounds__(256) void fused0b_kernel(
    const uint4* __restrict__ xbf, const int* __restrict__ off,
    const int* __restrict__ csr, const short8* __restrict__ wf,
    const float* __restrict__ b1, const float* __restrict__ b2,
    uint4* __restrict__ h0bf, int n) {
  __shared__ unsigned short zsA[64 * 72];
  __shared__ unsigned short zsB[64 * 72];
  const int tid = threadIdx.x;
  const int lane = tid & 63;
  const int wid = tid >> 6;
  const int n0 = blockIdx.x * 64;

  {
    const int node = tid >> 2;
    const int q4 = tid & 3;
    const int g = n0 + node;
    float a[8];
#pragma unroll
    for (int i = 0; i < 8; i++) a[i] = 0.f;
    if (g < n) {
      const uint4 u = xbf[(size_t)g * 4 + q4];
      a[0] = bflo(u.x); a[1] = bfhi(u.x); a[2] = bflo(u.y); a[3] = bfhi(u.y);
      a[4] = bflo(u.z); a[5] = bfhi(u.z); a[6] = bflo(u.w); a[7] = bfhi(u.w);
      const int e0 = off[g], e1 = off[g + 1];
      int e = e0;
      for (; e + 3 < e1; e += 4) {
        const int s0 = csr[e], s1 = csr[e + 1], s2 = csr[e + 2],
                  s3 = csr[e + 3];
        const uint4 u0 = xbf[(size_t)s0 * 4 + q4];
        const uint4 u1 = xbf[(size_t)s1 * 4 + q4];
        const uint4 u2 = xbf[(size_t)s2 * 4 + q4];
        const uint4 u3 = xbf[(size_t)s3 * 4 + q4];
        a[0] += bflo(u0.x) + bflo(u1.x) + bflo(u2.x) + bflo(u3.x);
        a[1] += bfhi(u0.x) + bfhi(u1.x) + bfhi(u2.x) + bfhi(u3.x);
        a[2] += bflo(u0.y) + bflo(u1.y) + bflo(u2.y) + bflo(u3.y);
        a[3] += bfhi(u0.y) + bfhi(u1.y) + bfhi(u2.y) + bfhi(u3.y);
        a[4] += bflo(u0.z) + bflo(u1.z) + bflo(u2.z) + bflo(u3.z);
        a[5] += bfhi(u0.z) + bfhi(u1.z) + bfhi(u2.z) + bfhi(u3.z);
        a[6] += bflo(u0.w) + bflo(u1.w) + bflo(u2.w) + bflo(u3.w);
        a[7] += bfhi(u0.w) + bfhi(u1.w) + bfhi(u2.w) + bfhi(u3.w);
      }
      for (; e < e1; ++e) {
        const uint4 u4 = xbf[(size_t)csr[e] * 4 + q4];
        a[0] += bflo(u4.x); a[1] += bfhi(u4.x);
        a[2] += bflo(u4.y); a[3] += bfhi(u4.y);
        a[4] += bflo(u4.z); a[5] += bfhi(u4.z);
        a[6] += bflo(u4.w); a[7] += bfhi(u4.w);
      }
    }
    uint4 w;
    w.x = packbf(a[0], a[1]); w.y = packbf(a[2], a[3]);
    w.z = packbf(a[4], a[5]); w.w = packbf(a[6], a[7]);
    *(uint4*)&zsA[node * 40 + q4 * 8] = w;
  }
  __syncthreads();
  gemm_stage<1, 4, true>(zsA, 40, zsB, wf + 0 * 64, b1, wid, lane);
  __syncthreads();
  gemm_stage<2, 4, false>(zsB, 72, zsA, wf + 4 * 64, b2, wid, lane);
  __syncthreads();

  for (int i = tid; i < 64 * 8; i += 256) {
    const int row = i >> 3, q = i & 7;
    if (n0 + row < n)
      ((short8*)h0bf)[(size_t)(n0 + row) * 8 + q] =
          *(const short8*)&zsA[row * 72 + q * 8];
  }
}

// ---------------------------------------------------------------------------
// fused1: gather(h0bf, D=64) -> GEMM(w1_1)+relu -> GEMM(w2_1) -> GEMM(cw1)
// +relu -> GEMM(cw2,N=16) -> out f32. 64 nodes/block, 4 threads/node
// (2 uint4 = 16 bf16 each), 4-deep edge unroll.
// ---------------------------------------------------------------------------
__global__ __launch_bounds__(256) void fused1_kernel(
    const uint4* __restrict__ hbf, const int* __restrict__ off,
    const int* __restrict__ csr, const short8* __restrict__ wf,
    const float* __restrict__ b1, const float* __restrict__ b2,
    const float* __restrict__ cb1, const float* __restrict__ cb2,
    float* __restrict__ out, int n) {
  __shared__ unsigned short zsA[64 * 72];
  __shared__ unsigned short zsB[64 * 72];
  const int tid = threadIdx.x;
  const int lane = tid & 63;
  const int wid = tid >> 6;
  const int n0 = blockIdx.x * 64;
  const int l15 = lane & 15, lh = lane >> 4;

  // gather: node = tid>>2, q4 = tid&3 owns uint4s [2q4, 2q4+1]
  {
    const int node = tid >> 2;
    const int q4 = tid & 3;
    const int g = n0 + node;
    float a[16];
#pragma unroll
    for (int i = 0; i < 16; i++) a[i] = 0.f;
    if (g < n) {
      const uint4* base = hbf + (size_t)g * 8 + q4 * 2;
      const uint4 ua = base[0], ub = base[1];
      a[0] = bflo(ua.x); a[1] = bfhi(ua.x); a[2] = bflo(ua.y); a[3] = bfhi(ua.y);
      a[4] = bflo(ua.z); a[5] = bfhi(ua.z); a[6] = bflo(ua.w); a[7] = bfhi(ua.w);
      a[8] = bflo(ub.x); a[9] = bfhi(ub.x); a[10] = bflo(ub.y); a[11] = bfhi(ub.y);
      a[12] = bflo(ub.z); a[13] = bfhi(ub.z); a[14] = bflo(ub.w); a[15] = bfhi(ub.w);
      const int e0 = off[g], e1 = off[g + 1];
      int e = e0;
      for (; e + 3 < e1; e += 4) {
        const int s0 = csr[e], s1 = csr[e + 1], s2 = csr[e + 2],
                  s3 = csr[e + 3];
        const uint4* p0 = hbf + (size_t)s0 * 8 + q4 * 2;
        const uint4* p1 = hbf + (size_t)s1 * 8 + q4 * 2;
        const uint4* p2 = hbf + (size_t)s2 * 8 + q4 * 2;
        const uint4* p3 = hbf + (size_t)s3 * 8 + q4 * 2;
        uint4 v0a = p0[0], v0b = p0[1], v1a = p1[0], v1b = p1[1];
        uint4 v2a = p2[0], v2b = p2[1], v3a = p3[0], v3b = p3[1];
        a[0] += bflo(v0a.x) + bflo(v1a.x) + bflo(v2a.x) + bflo(v3a.x);
        a[1] += bfhi(v0a.x) + bfhi(v1a.x) + bfhi(v2a.x) + bfhi(v3a.x);
        a[2] += bflo(v0a.y) + bflo(v1a.y) + bflo(v2a.y) + bflo(v3a.y);
        a[3] += bfhi(v0a.y) + bfhi(v1a.y) + bfhi(v2a.y) + bfhi(v3a.y);
        a[4] += bflo(v0a.z) + bflo(v1a.z) + bflo(v2a.z) + bflo(v3a.z);
        a[5] += bfhi(v0a.z) + bfhi(v1a.z) + bfhi(v2a.z) + bfhi(v3a.z);
        a[6] += bflo(v0a.w) + bflo(v1a.w) + bflo(v2a.w) + bflo(v3a.w);
        a[7] += bfhi(v0a.w) + bfhi(v1a.w) + bfhi(v2a.w) + bfhi(v3a.w);
        a[8] += bflo(v0b.x) + bflo(v1b.x) + bflo(v2b.x) + bflo(v3b.x);
        a[9] += bfhi(v0b.x) + bfhi(v1b.x) + bfhi(v2b.x) + bfhi(v3b.x);
        a[10] += bflo(v0b.y) + bflo(v1b.y) + bflo(v2b.y) + bflo(v3b.y);
        a[11] += bfhi(v0b.y) + bfhi(v1b.y) + bfhi(v2b.y) + bfhi(v3b.y);
        a[12] += bflo(v0b.z) + bflo(v1b.z) + bflo(v2b.z) + bflo(v3b.z);
        a[13] += bfhi(v0b.z) + bfhi(v1b.z) + bfhi(v2b.z) + bfhi(v3b.z);
        a[14] += bflo(v0b.w) + bflo(v1b.w) + bflo(v2b.w) + bflo(v3b.w);
        a[15] += bfhi(v0b.w) + bfhi(v1b.w) + bfhi(v2b.w) + bfhi(v3b.w);
      }
      for (; e < e1; ++e) {
        const uint4* p = hbf + (size_t)csr[e] * 8 + q4 * 2;
        const uint4 wa = p[0], wb = p[1];
        a[0] += bflo(wa.x); a[1] += bfhi(wa.x);
        a[2] += bflo(wa.y); a[3] += bfhi(wa.y);
        a[4] += bflo(wa.z); a[5] += bfhi(wa.z);
        a[6] += bflo(wa.w); a[7] += bfhi(wa.w);
        a[8] += bflo(wb.x); a[9] += bfhi(wb.x);
        a[10] += bflo(wb.y); a[11] += bfhi(wb.y);
        a[12] += bflo(wb.z); a[13] += bfhi(wb.z);
        a[14] += bflo(wb.w); a[15] += bfhi(wb.w);
      }
    }
#pragma unroll
    for (int h = 0; h < 2; h++) {
      uint4 w;
      w.x = packbf(a[h * 8 + 0], a[h * 8 + 1]);
      w.y = packbf(a[h * 8 + 2], a[h * 8 + 3]);
      w.z = packbf(a[h * 8 + 4], a[h * 8 + 5]);
      w.w = packbf(a[h * 8 + 6], a[h * 8 + 7]);
      *(uint4*)&zsA[node * 72 + q4 * 16 + h * 8] = w;
    }
  }
  __syncthreads();
  gemm_stage<2, 4, true>(zsA, 72, zsB, wf + 12 * 64, b1, wid, lane);   // z1
  __syncthreads();
  gemm_stage<2, 4, false>(zsB, 72, zsA, wf + 20 * 64, b2, wid, lane);  // h1
  __syncthreads();
  gemm_stage<2, 4, true>(zsA, 72, zsB, wf + 28 * 64, cb1, wid, lane);  // z2
  __syncthreads();

  // GEMM4: K=64, N=16 (cw2) -> f32 out
  {
    const short8 bf0 = wf[36 * 64 + lane];
    const short8 bf1 = wf[37 * 64 + lane];
    f32x4 acc = (f32x4){0.f, 0.f, 0.f, 0.f};
#pragma unroll
    for (int kb = 0; kb < 2; kb++) {
      const short8 a =
          *(const short8*)&zsB[(wid * 16 + l15) * 72 + kb * 32 + lh * 8];
      acc = __builtin_amdgcn_mfma_f32_16x16x32_bf16(a, kb ? bf1 : bf0, acc, 0,
                                                    0, 0);
    }
    __syncthreads();
    float* zf = (float*)zsA;  // [64][20] f32
    const float bb = cb2[l15];
#pragma unroll
    for (int r = 0; r < 4; r++)
      zf[(wid * 16 + lh * 4 + r) * 20 + l15] = acc[r] + bb;
    __syncthreads();
    for (int i = tid; i < 256; i += 256) {
      const int row = i >> 2, q = i & 3;
      if (n0 + row < n)
        ((float4*)out)[(size_t)(n0 + row) * 4 + q] =
            *(const float4*)&zf[row * 20 + q * 4];
    }
  }
}

extern "C" void kernel_launch(void* const* d_in, const int* in_sizes, int n_in,
                              void* d_out, int out_size, void* d_ws,
                              size_t ws_size, hipStream_t stream) {
  const float* x = (const float*)d_in[0];
  const int* ei = (const int*)d_in[1];
  const float* w1_0 = (const float*)d_in[2];
  const float* b1_0 = (const float*)d_in[3];
  const float* w2_0 = (const float*)d_in[4];
  const float* b2_0 = (const float*)d_in[5];
  const float* w1_1 = (const float*)d_in[6];
  const float* b1_1 = (const float*)d_in[7];
  const float* w2_1 = (const float*)d_in[8];
  const float* b2_1 = (const float*)d_in[9];
  const float* cw1 = (const float*)d_in[10];
  const float* cb1 = (const float*)d_in[11];
  const float* cw2 = (const float*)d_in[12];
  const float* cb2 = (const float*)d_in[13];

  const int n = in_sizes[0] / 32;  // nodes (< 2^17 for packing)
  const int ne = in_sizes[1] / 2;  // edges
  const int* src = ei;
  const int* dst = ei + ne;
  const int nb = (n + NPB - 1) / NPB;

  // Workspace layout (16B-aligned uint4 region first, then ints)
  uint4* h0bf = (uint4*)d_ws;                  // n*8  (bf16 [n][64])
  uint4* xbf = h0bf + (size_t)n * 8;           // n*4  (bf16 [n][32])
  uint4* wfrag = xbf + (size_t)n * 4;          // 38*64
  int* sorted = (int*)(wfrag + 38 * 64);       // ne
  int* csr = sorted + ne;                      // ne
  int* off = csr + ne;                         // n+1
  int* bcnt = off + n + 1;                     // nb
  int* boff = bcnt + nb;                       // nb+1
  int* bcur = boff + nb + 1;                   // nb

  // prep first: zeroes bcnt, builds xbf + wfrag
  {
    const int n4 = n * 8;
    prep_kernel<<<1 + (n4 + 255) / 256, 256, 0, stream>>>(
        (const float4*)x, (uint2*)xbf, n4, w1_0, w2_0, w1_1, w2_1, cw1, cw2,
        wfrag, bcnt, nb);
  }

  // --- CSR build ---
  bucket_hist_kernel<<<220, 256, 0, stream>>>(dst, bcnt, ne, nb);
  bucket_scan_kernel<<<1, 512, 0, stream>>>(bcnt, boff, bcur, nb, ne);
  partition_kernel<<<(ne + CHUNK - 1) / CHUNK, 256, 0, stream>>>(
      src, dst, bcur, sorted, ne, nb);
  fill_bucket_kernel<<<nb, 256, 0, stream>>>(sorted, boff, off, csr, n, ne);

  const int ntile = (n + 63) / 64;
  const short8* wf = (const short8*)wfrag;

  fused0b_kernel<<<ntile, 256, 0, stream>>>(xbf, off, csr, wf, b1_0, b2_0,
                                            h0bf, n);
  fused1_kernel<<<ntile, 256, 0, stream>>>(h0bf, off, csr, wf, b1_1, b2_1,
                                           cb1, cb2, (float*)d_out, n);
}